// Round 1
// baseline (594.508 us; speedup 1.0000x reference)
//
#include <hip/hip_runtime.h>
#include <hip/hip_bf16.h>

typedef __hip_bfloat16 bf16;
typedef __attribute__((ext_vector_type(8))) short v8s;
typedef __attribute__((ext_vector_type(4))) float v4f;

__device__ __forceinline__ float b2f(bf16 v){ return __bfloat162float(v); }
__device__ __forceinline__ bf16  f2b(float v){ return __float2bfloat16(v); }

// Inputs may be bf16 OR f32 — runtime-detected flag (1 => f32). Output dtype follows.
__device__ __forceinline__ float ldin(const void* p, int i, bool f32in){
  return f32in ? ((const float*)p)[i] : b2f(((const bf16*)p)[i]);
}

// stage 4 consecutive source elems (f32-or-bf16) into dst as bf16 (8B write)
__device__ __forceinline__ void stage4(const void* src, size_t off, bool f32in, bf16* dst){
  union { bf16 h[4]; ushort4 u; } tmp;
  if (f32in){
    float4 f = *(const float4*)((const float*)src + off);
    tmp.h[0] = f2b(f.x); tmp.h[1] = f2b(f.y); tmp.h[2] = f2b(f.z); tmp.h[3] = f2b(f.w);
  } else {
    tmp.u = *(const ushort4*)((const ushort*)src + off);
  }
  *(ushort4*)dst = tmp.u;
}
__device__ __forceinline__ void stage4b(const bf16* src, bf16* dst){
  *(ushort4*)dst = *(const ushort4*)src;
}

// Problem: B=2, C=512, T=16, H=W=24, heads=8, ch=64
// ws: flag | A (S) | A2 (S) | Bq (3S) | Cx 9,437,184 | [Cx2 9,437,184 if room]
// Cx2 = x2 in [m][t][c] layout so gn_t reads coalesced (R11: gn_t gather was
// 2B loads at 18KB stride).

// ---------------------------------------------------------------- detect input dtype
__global__ void k_detect(const void* x, int* flag){
  int tid = threadIdx.x;
  const bf16* p = (const bf16*)x;
  int cnt = 0;
  for (int i = tid; i < 512; i += 64){
    float v = b2f(p[i]);
    if (!(fabsf(v) <= 64.f)) cnt++;
  }
  #pragma unroll
  for (int off = 32; off; off >>= 1) cnt += __shfl_down(cnt, off, 64);
  if (tid == 0) flag[0] = (cnt > 16) ? 1 : 0;
}

// ---------------------------------------------------------------- weight convert -> bf16 scratch
__global__ __launch_bounds__(256) void k_cvtw(const void* __restrict__ W,
        bf16* __restrict__ out, int n4, const int* __restrict__ flag){
  const bool f32in = flag[0] != 0;
  int i = blockIdx.x*256 + threadIdx.x;
  if (i < n4) stage4(W, (size_t)i*4, f32in, out + (size_t)i*4);
}

// ---------------------------------------------------------------- K1: spatial groupnorm -> xnT [l][c]
__global__ __launch_bounds__(256) void k_gn_s(const void* __restrict__ x,
        const void* __restrict__ gw, const void* __restrict__ gb,
        bf16* __restrict__ xnT, const int* __restrict__ flag, int n0){
  const bool f32in = flag[0] != 0;
  const int g = blockIdx.x;
  const int nl = blockIdx.y;
  const int n = n0 + nl;
  const int b = n >> 4, t = n & 15;
  const int tid = threadIdx.x;
  __shared__ float xs[576*17];     // [l][cg] padded
  __shared__ float red[4][2];
  __shared__ float stats[2];
  float s = 0.f, q = 0.f;
  for (int i = tid; i < 9216; i += 256){
    int cg = i / 576, l = i - cg*576;
    int c = g*16 + cg;
    float v = ldin(x, ((b*512 + c)*16 + t)*576 + l, f32in);
    xs[l*17 + cg] = v; s += v; q += v*v;
  }
  #pragma unroll
  for (int off = 32; off; off >>= 1){ s += __shfl_down(s, off, 64); q += __shfl_down(q, off, 64); }
  int wid = tid >> 6;
  if ((tid & 63) == 0){ red[wid][0] = s; red[wid][1] = q; }
  __syncthreads();
  if (tid == 0){
    float S = red[0][0]+red[1][0]+red[2][0]+red[3][0];
    float Q = red[0][1]+red[1][1]+red[2][1]+red[3][1];
    float mean = S * (1.f/9216.f);
    float var  = Q * (1.f/9216.f) - mean*mean;
    stats[0] = mean; stats[1] = rsqrtf(fmaxf(var, 0.f) + 1e-5f);
  }
  __syncthreads();
  float mean = stats[0], rstd = stats[1];
  for (int i = tid; i < 9216; i += 256){
    int l = i >> 4, cg = i & 15;
    int c = g*16 + cg;
    xnT[(size_t)(nl*576 + l)*512 + c] =
        f2b((xs[l*17 + cg] - mean)*rstd*ldin(gw, c, f32in) + ldin(gb, c, f32in));
  }
}

// ---------------------------------------------------------------- K2: spatial qkv GEMM (MFMA, XCD-swizzled)
__global__ __launch_bounds__(256) void k_qkv_s_mfma(const bf16* __restrict__ XT,
        const bf16* __restrict__ Wb, const void* __restrict__ Bv,
        bf16* __restrict__ Y, const int* __restrict__ flag,
        size_t kOff, size_t vOff){
  const bool f32in = flag[0] != 0;
  const int bid = blockIdx.x;
  const int xcd = bid & 7, slot = bid >> 3;
  const int grp_local = slot / 12, oi = slot - grp_local*12;
  const int group = xcd + 8*grp_local;      // 0..9*NCH-1
  const int nl = group / 9;
  const int l0 = (group - nl*9) * 64;
  const int o0 = oi * 128;
  const int tid = threadIdx.x, lane = tid & 63;
  const int wm = (tid >> 6) & 1, wn = tid >> 7;
  const int r15 = lane & 15, quad = lane >> 4;
  __shared__ bf16 As[64*72];
  __shared__ bf16 Bs[128*72];
  v4f acc[2][4];
  #pragma unroll
  for (int i = 0; i < 2; ++i)
    #pragma unroll
    for (int j = 0; j < 4; ++j) acc[i][j] = (v4f){0.f,0.f,0.f,0.f};
  for (int kc = 0; kc < 512; kc += 64){
    __syncthreads();
    #pragma unroll
    for (int r = 0; r < 4; ++r){
      int e4 = (tid + 256*r)*4;
      int row = e4 >> 6, k = e4 & 63;
      stage4b(&XT[(size_t)(nl*576 + l0 + row)*512 + kc + k], &As[row*72 + k]);
    }
    #pragma unroll
    for (int r = 0; r < 8; ++r){
      int e4 = (tid + 256*r)*4;
      int row = e4 >> 6, k = e4 & 63;
      stage4b(&Wb[(size_t)(o0+row)*512 + kc + k], &Bs[row*72 + k]);
    }
    __syncthreads();
    #pragma unroll
    for (int ks = 0; ks < 2; ++ks){
      v8s a[2], b[4];
      #pragma unroll
      for (int mi = 0; mi < 2; ++mi)
        a[mi] = *(const v8s*)&As[(wm*32 + mi*16 + r15)*72 + ks*32 + quad*8];
      #pragma unroll
      for (int ni = 0; ni < 4; ++ni)
        b[ni] = *(const v8s*)&Bs[(wn*64 + ni*16 + r15)*72 + ks*32 + quad*8];
      #pragma unroll
      for (int mi = 0; mi < 2; ++mi)
        #pragma unroll
        for (int ni = 0; ni < 4; ++ni)
          acc[mi][ni] = __builtin_amdgcn_mfma_f32_16x16x32_bf16(a[mi], b[ni], acc[mi][ni], 0, 0, 0);
    }
  }
  const int seg = o0 >> 9;  // 0=Q,1=K,2=V
  size_t segbase = ((seg==0) ? 0 : (seg==1) ? kOff : vOff) + (size_t)nl*294912;
  const int ob = o0 & 511;
  #pragma unroll
  for (int mi = 0; mi < 2; ++mi)
    #pragma unroll
    for (int ni = 0; ni < 4; ++ni){
      int oseg = ob + wn*64 + ni*16 + r15;
      float bia = ldin(Bv, o0 + wn*64 + ni*16 + r15, f32in);
      #pragma unroll
      for (int rg = 0; rg < 4; ++rg){
        int l = l0 + wm*32 + mi*16 + quad*4 + rg;
        float val = acc[mi][ni][rg] + bia;
        size_t dst = (seg==2) ? segbase + (size_t)oseg*576 + l
                              : segbase + (size_t)l*512 + oseg;
        Y[dst] = f2b(val);
      }
    }
}

// ---------------------------------------------------------------- K3: spatial attention (flash MFMA) -> attT [l][c]
__global__ __launch_bounds__(256, 4) void k_attn_s_mfma(const bf16* __restrict__ qkv,
        bf16* __restrict__ attT, size_t kOff, size_t vOff){
  const int bid = blockIdx.x;
  const int xcd = bid & 7, slot = bid >> 3;
  const int nl = xcd + 8*(slot/72);
  const int idx = slot - 72*(slot/72);
  const int head = idx/9, t0 = idx - 9*head;
  const int tid = threadIdx.x, lane = tid & 63, w = tid >> 6;
  const int r15 = lane & 15, quad = lane >> 4;
  __shared__ bf16 Ks[64*72];
  __shared__ bf16 Vs[64*72];
  __shared__ bf16 Ps[4][16*72];
  const bf16* QT = qkv + (size_t)nl*294912;
  const bf16* KT = qkv + kOff + (size_t)nl*294912;
  const bf16* Vp = qkv + vOff + (size_t)nl*294912;
  const int c0 = head*64;
  v8s aq0, aq1;
  {
    const bf16* qrow = QT + (size_t)(t0*64 + w*16 + r15)*512 + c0;
    aq0 = *(const v8s*)(qrow + quad*8);
    aq1 = *(const v8s*)(qrow + 32 + quad*8);
  }
  v4f oc[4];
  #pragma unroll
  for (int ni = 0; ni < 4; ++ni) oc[ni] = (v4f){0.f,0.f,0.f,0.f};
  float m_run[4] = {-1e30f,-1e30f,-1e30f,-1e30f};
  float l_run[4] = {0.f,0.f,0.f,0.f};
  for (int sc = 0; sc < 9; ++sc){
    __syncthreads();
    #pragma unroll
    for (int r = 0; r < 4; ++r){
      int e4 = (tid + 256*r)*4;
      int row = e4 >> 6, col = e4 & 63;
      stage4b(&KT[(size_t)(sc*64 + row)*512 + c0 + col], &Ks[row*72 + col]);
      stage4b(&Vp[(size_t)(c0 + row)*576 + sc*64 + col], &Vs[row*72 + col]);
    }
    __syncthreads();
    v4f sa[4];
    #pragma unroll
    for (int sj = 0; sj < 4; ++sj) sa[sj] = (v4f){0.f,0.f,0.f,0.f};
    #pragma unroll
    for (int sj = 0; sj < 4; ++sj){
      v8s b0 = *(const v8s*)&Ks[(sj*16 + r15)*72 + quad*8];
      v8s b1 = *(const v8s*)&Ks[(sj*16 + r15)*72 + 32 + quad*8];
      sa[sj] = __builtin_amdgcn_mfma_f32_16x16x32_bf16(aq0, b0, sa[sj], 0, 0, 0);
      sa[sj] = __builtin_amdgcn_mfma_f32_16x16x32_bf16(aq1, b1, sa[sj], 0, 0, 0);
    }
    float cmx[4] = {-1e30f,-1e30f,-1e30f,-1e30f};
    #pragma unroll
    for (int sj = 0; sj < 4; ++sj)
      #pragma unroll
      for (int rg = 0; rg < 4; ++rg){
        float v = sa[sj][rg]*0.125f;
        sa[sj][rg] = v;
        cmx[rg] = fmaxf(cmx[rg], v);
      }
    #pragma unroll
    for (int off = 1; off < 16; off <<= 1)
      #pragma unroll
      for (int rg = 0; rg < 4; ++rg) cmx[rg] = fmaxf(cmx[rg], __shfl_xor(cmx[rg], off, 64));
    float alpha[4];
    #pragma unroll
    for (int rg = 0; rg < 4; ++rg){
      float mnew = fmaxf(m_run[rg], cmx[rg]);
      alpha[rg] = __expf(m_run[rg] - mnew);
      m_run[rg] = mnew;
    }
    float psum[4] = {0.f,0.f,0.f,0.f};
    #pragma unroll
    for (int sj = 0; sj < 4; ++sj)
      #pragma unroll
      for (int rg = 0; rg < 4; ++rg){
        float e = __expf(sa[sj][rg] - m_run[rg]);
        sa[sj][rg] = e; psum[rg] += e;
      }
    #pragma unroll
    for (int off = 1; off < 16; off <<= 1)
      #pragma unroll
      for (int rg = 0; rg < 4; ++rg) psum[rg] += __shfl_xor(psum[rg], off, 64);
    #pragma unroll
    for (int rg = 0; rg < 4; ++rg) l_run[rg] = l_run[rg]*alpha[rg] + psum[rg];
    #pragma unroll
    for (int ni = 0; ni < 4; ++ni)
      #pragma unroll
      for (int rg = 0; rg < 4; ++rg) oc[ni][rg] *= alpha[rg];
    #pragma unroll
    for (int sj = 0; sj < 4; ++sj)
      #pragma unroll
      for (int rg = 0; rg < 4; ++rg)
        Ps[w][(quad*4 + rg)*72 + sj*16 + r15] = f2b(sa[sj][rg]);
    #pragma unroll
    for (int ks = 0; ks < 2; ++ks){
      v8s a = *(const v8s*)&Ps[w][r15*72 + ks*32 + quad*8];
      #pragma unroll
      for (int ni = 0; ni < 4; ++ni){
        v8s b = *(const v8s*)&Vs[(ni*16 + r15)*72 + ks*32 + quad*8];
        oc[ni] = __builtin_amdgcn_mfma_f32_16x16x32_bf16(a, b, oc[ni], 0, 0, 0);
      }
    }
  }
  float inv[4];
  #pragma unroll
  for (int rg = 0; rg < 4; ++rg) inv[rg] = 1.f / l_run[rg];
  #pragma unroll
  for (int ni = 0; ni < 4; ++ni)
    #pragma unroll
    for (int rg = 0; rg < 4; ++rg){
      int t = t0*64 + w*16 + quad*4 + rg;
      attT[(size_t)(nl*576 + t)*512 + c0 + ni*16 + r15] = f2b(oc[ni][rg]*inv[rg]);
    }
}

// ---------------------------------------------------------------- K4: spatial proj + residual (MFMA)
// Optionally dual-writes x2T [m][t][c] so gn_t reads coalesced (doT gate).
__global__ __launch_bounds__(256) void k_proj_s_mfma(const bf16* __restrict__ AT,
        const void* __restrict__ W, const void* __restrict__ Bv,
        const void* __restrict__ xin, bf16* __restrict__ x2,
        bf16* __restrict__ x2T, int doT,
        const int* __restrict__ flag, int n0){
  const bool f32in = flag[0] != 0;
  const int o0 = blockIdx.x * 128;
  const int l0 = blockIdx.y * 64;
  const int nl = blockIdx.z;
  const int n = n0 + nl;
  const int b = n >> 4, t = n & 15;
  const int tid = threadIdx.x, lane = tid & 63;
  const int wm = (tid >> 6) & 1, wn = tid >> 7;
  const int r15 = lane & 15, quad = lane >> 4;
  __shared__ bf16 As[128*72];
  __shared__ bf16 Bs[64*72];
  v4f acc[4][2];
  #pragma unroll
  for (int i = 0; i < 4; ++i)
    #pragma unroll
    for (int j = 0; j < 2; ++j) acc[i][j] = (v4f){0.f,0.f,0.f,0.f};
  for (int kc = 0; kc < 512; kc += 64){
    __syncthreads();
    #pragma unroll
    for (int r = 0; r < 8; ++r){
      int e4 = (tid + 256*r)*4;
      int row = e4 >> 6, k = e4 & 63;
      stage4(W, (size_t)(o0+row)*512 + kc + k, f32in, &As[row*72 + k]);
    }
    #pragma unroll
    for (int r = 0; r < 4; ++r){
      int e4 = (tid + 256*r)*4;
      int row = e4 >> 6, k = e4 & 63;
      stage4b(&AT[(size_t)(nl*576 + l0 + row)*512 + kc + k], &Bs[row*72 + k]);
    }
    __syncthreads();
    #pragma unroll
    for (int ks = 0; ks < 2; ++ks){
      v8s a[4], b[2];
      #pragma unroll
      for (int mi = 0; mi < 4; ++mi)
        a[mi] = *(const v8s*)&As[(wm*64 + mi*16 + r15)*72 + ks*32 + quad*8];
      #pragma unroll
      for (int ni = 0; ni < 2; ++ni)
        b[ni] = *(const v8s*)&Bs[(wn*32 + ni*16 + r15)*72 + ks*32 + quad*8];
      #pragma unroll
      for (int mi = 0; mi < 4; ++mi)
        #pragma unroll
        for (int ni = 0; ni < 2; ++ni)
          acc[mi][ni] = __builtin_amdgcn_mfma_f32_16x16x32_bf16(a[mi], b[ni], acc[mi][ni], 0, 0, 0);
    }
  }
  #pragma unroll
  for (int mi = 0; mi < 4; ++mi)
    #pragma unroll
    for (int rg = 0; rg < 4; ++rg){
      int o = o0 + wm*64 + mi*16 + quad*4 + rg;
      float bia = ldin(Bv, o, f32in);
      #pragma unroll
      for (int ni = 0; ni < 2; ++ni){
        int l = l0 + wn*32 + ni*16 + r15;
        size_t addr = ((size_t)(b*512 + o)*16 + t)*576 + l;
        bf16 v = f2b(acc[mi][ni][rg] + bia + ldin(xin, addr, f32in));
        x2[addr] = v;
        if (doT) x2T[(size_t)(b*576 + l)*8192 + t*512 + o] = v;
      }
    }
}

// ---------------------------------------------------------------- K5a: temporal groupnorm (scattered x2) -> xnT [m][t][c]
__global__ __launch_bounds__(256) void k_gn_t(const bf16* __restrict__ x2,
        const void* __restrict__ gw, const void* __restrict__ gb,
        bf16* __restrict__ xnT, const int* __restrict__ flag, int m0){
  const bool f32in = flag[0] != 0;
  const int ml = blockIdx.x;
  const int m = m0 + ml;
  const int b = m / 576, l = m - b*576;
  const int tid = threadIdx.x;
  __shared__ float xs[8192];
  __shared__ float mg[32], rg[32];
  for (int i = tid; i < 8192; i += 256){
    int t = i >> 9, c = i & 511;
    xs[i] = b2f(x2[((b*512 + c)*16 + t)*576 + l]);
  }
  __syncthreads();
  {
    int g = tid >> 3, ii = tid & 7;
    float s = 0.f, q = 0.f;
    for (int idx = ii; idx < 256; idx += 8){
      int t = idx >> 4, cg = idx & 15;
      float v = xs[t*512 + g*16 + cg]; s += v; q += v*v;
    }
    #pragma unroll
    for (int off = 1; off < 8; off <<= 1){ s += __shfl_xor(s, off, 64); q += __shfl_xor(q, off, 64); }
    if (ii == 0){
      float mean = s*(1.f/256.f);
      float var  = q*(1.f/256.f) - mean*mean;
      mg[g] = mean; rg[g] = rsqrtf(fmaxf(var, 0.f) + 1e-5f);
    }
  }
  __syncthreads();
  for (int i = tid; i < 8192; i += 256){
    int c = i & 511, g = c >> 4;
    xnT[(size_t)ml*8192 + i] = f2b((xs[i] - mg[g])*rg[g]*ldin(gw, c, f32in) + ldin(gb, c, f32in));
  }
}

// ---------------------------------------------------------------- K5b: temporal groupnorm (coalesced x2T)
__global__ __launch_bounds__(256) void k_gn_t2(const bf16* __restrict__ x2T,
        const void* __restrict__ gw, const void* __restrict__ gb,
        bf16* __restrict__ xnT, const int* __restrict__ flag, int m0){
  const bool f32in = flag[0] != 0;
  const int ml = blockIdx.x;
  const int m = m0 + ml;
  const int tid = threadIdx.x;
  __shared__ float xs[8192];
  __shared__ float mg[32], rg[32];
  for (int i = tid; i < 8192; i += 256)
    xs[i] = b2f(x2T[(size_t)m*8192 + i]);     // [t][c] order, fully coalesced
  __syncthreads();
  {
    int g = tid >> 3, ii = tid & 7;
    float s = 0.f, q = 0.f;
    for (int idx = ii; idx < 256; idx += 8){
      int t = idx >> 4, cg = idx & 15;
      float v = xs[t*512 + g*16 + cg]; s += v; q += v*v;
    }
    #pragma unroll
    for (int off = 1; off < 8; off <<= 1){ s += __shfl_xor(s, off, 64); q += __shfl_xor(q, off, 64); }
    if (ii == 0){
      float mean = s*(1.f/256.f);
      float var  = q*(1.f/256.f) - mean*mean;
      mg[g] = mean; rg[g] = rsqrtf(fmaxf(var, 0.f) + 1e-5f);
    }
  }
  __syncthreads();
  for (int i = tid; i < 8192; i += 256){
    int c = i & 511, g = c >> 4;
    xnT[(size_t)ml*8192 + i] = f2b((xs[i] - mg[g])*rg[g]*ldin(gw, c, f32in) + ldin(gb, c, f32in));
  }
}

// ---------------------------------------------------------------- K6: temporal qkv GEMM (MFMA, XCD-swizzled, 4 m per block)
__global__ __launch_bounds__(256) void k_qkv_t_mfma(const bf16* __restrict__ XT,
        const bf16* __restrict__ Wb, const void* __restrict__ Bv,
        bf16* __restrict__ Y, const int* __restrict__ flag){
  const bool f32in = flag[0] != 0;
  const int bid = blockIdx.x;
  const int xcd = bid & 7, slot = bid >> 3;
  const int grp_local = slot / 12, oi = slot - grp_local*12;
  const int mg0 = (xcd + 8*grp_local) * 4;
  const int o0 = oi * 128;
  const int tid = threadIdx.x, lane = tid & 63;
  const int wm = (tid >> 6) & 1, wn = tid >> 7;
  const int r15 = lane & 15, quad = lane >> 4;
  __shared__ bf16 As[128*72];
  __shared__ bf16 Bs[64*72];
  v4f acc[4][2];
  #pragma unroll
  for (int i = 0; i < 4; ++i)
    #pragma unroll
    for (int j = 0; j < 2; ++j) acc[i][j] = (v4f){0.f,0.f,0.f,0.f};
  for (int kc = 0; kc < 512; kc += 64){
    __syncthreads();
    #pragma unroll
    for (int r = 0; r < 8; ++r){
      int e4 = (tid + 256*r)*4;
      int row = e4 >> 6, k = e4 & 63;
      stage4b(&Wb[(size_t)(o0+row)*512 + kc + k], &As[row*72 + k]);
    }
    #pragma unroll
    for (int r = 0; r < 4; ++r){
      int e4 = (tid + 256*r)*4;
      int row = e4 >> 6, k = e4 & 63;
      stage4b(&XT[(size_t)(mg0 + (row >> 4))*8192 + (row & 15)*512 + kc + k], &Bs[row*72 + k]);
    }
    __syncthreads();
    #pragma unroll
    for (int ks = 0; ks < 2; ++ks){
      v8s a[4], b[2];
      #pragma unroll
      for (int mi = 0; mi < 4; ++mi)
        a[mi] = *(const v8s*)&As[(wm*64 + mi*16 + r15)*72 + ks*32 + quad*8];
      #pragma unroll
      for (int ni = 0; ni < 2; ++ni)
        b[ni] = *(const v8s*)&Bs[(wn*32 + ni*16 + r15)*72 + ks*32 + quad*8];
      #pragma unroll
      for (int mi = 0; mi < 4; ++mi)
        #pragma unroll
        for (int ni = 0; ni < 2; ++ni)
          acc[mi][ni] = __builtin_amdgcn_mfma_f32_16x16x32_bf16(a[mi], b[ni], acc[mi][ni], 0, 0, 0);
    }
  }
  #pragma unroll
  for (int mi = 0; mi < 4; ++mi)
    #pragma unroll
    for (int rg = 0; rg < 4; ++rg){
      int o = o0 + wm*64 + mi*16 + quad*4 + rg;
      float bia = ldin(Bv, o, f32in);
      #pragma unroll
      for (int ni = 0; ni < 2; ++ni){
        int nidx = wn*32 + ni*16 + r15;
        int mb = nidx >> 4, t = nidx & 15;
        Y[((size_t)(mg0 + mb)*1536 + o)*16 + t] = f2b(acc[mi][ni][rg] + bia);
      }
    }
}

// ---------------------------------------------------------------- K7: temporal attention -> attT [m][t][c]
// float4-vectorized: q/k/v transposed to [t][c] in LDS (R11: 384 scalar
// ds_read/thread made this LDS-instruction-bound at 96 us).
__global__ __launch_bounds__(256) void k_attn_t(const bf16* __restrict__ qkv,
        const void* __restrict__ tbk, const void* __restrict__ tbv,
        bf16* __restrict__ attT, const int* __restrict__ flag){
  const bool f32in = flag[0] != 0;
  const int head = blockIdx.x;
  const int ml = blockIdx.y;
  const int tid = threadIdx.x;
  __shared__ float qsT[16*68], ksT[16*68], vsT[16*68];  // [t][c], stride 68 (16B-aligned rows)
  __shared__ float tks[33*68], tvs[33*68];              // [d][c]
  __shared__ float ps[16*17];
  const int base = (ml*1536 + head*64)*16;
  for (int i = tid; i < 1024; i += 256){
    int c = i >> 4, t = i & 15;
    qsT[t*68 + c] = b2f(qkv[base + i]);
    ksT[t*68 + c] = b2f(qkv[base + 8192 + i]);
    vsT[t*68 + c] = b2f(qkv[base + 16384 + i]);
  }
  for (int i = tid; i < 33*64; i += 256){
    int d = i >> 6, c = i & 63;
    tks[d*68 + c] = ldin(tbk, i, f32in);
    tvs[d*68 + c] = ldin(tbv, i, f32in);
  }
  __syncthreads();
  {
    const int t = tid >> 4, s = tid & 15;
    const float4* qt = (const float4*)&qsT[t*68];
    const float4* kr = (const float4*)&ksT[s*68];
    const float4* q2 = (const float4*)&qsT[s*68];
    const float4* tr = (const float4*)&tks[(t - s + 16)*68];
    float qk = 0.f, rp = 0.f;
    #pragma unroll
    for (int c4 = 0; c4 < 16; ++c4){
      float4 a = qt[c4], b = kr[c4];
      qk += a.x*b.x + a.y*b.y + a.z*b.z + a.w*b.w;
      float4 a2 = q2[c4], tb = tr[c4];
      rp += a2.x*tb.x + a2.y*tb.y + a2.z*tb.z + a2.w*tb.w;
    }
    float logit = 0.125f*qk + 0.35355339059327373f*rp;
    if (s > t) logit = -1e8f;
    float mx = logit;
    #pragma unroll
    for (int off = 8; off; off >>= 1) mx = fmaxf(mx, __shfl_xor(mx, off, 16));
    float e = __expf(logit - mx);
    float tot = e;
    #pragma unroll
    for (int off = 8; off; off >>= 1) tot += __shfl_xor(tot, off, 16);
    ps[t*17 + s] = e / tot;
  }
  __syncthreads();
  {
    const int c4 = tid & 15, t = tid >> 4;
    float4 acc = {0.f,0.f,0.f,0.f};
    #pragma unroll
    for (int s = 0; s < 16; ++s){
      float p = ps[t*17 + s];
      float4 v4 = *(const float4*)&vsT[s*68 + c4*4];
      float4 t4 = *(const float4*)&tvs[(s - t + 16)*68 + c4*4];
      acc.x += p*(v4.x + t4.x); acc.y += p*(v4.y + t4.y);
      acc.z += p*(v4.z + t4.z); acc.w += p*(v4.w + t4.w);
    }
    union { bf16 h[4]; ushort4 u; } o;
    o.h[0] = f2b(acc.x); o.h[1] = f2b(acc.y); o.h[2] = f2b(acc.z); o.h[3] = f2b(acc.w);
    *(ushort4*)&attT[(size_t)ml*8192 + t*512 + head*64 + c4*4] = o.u;
  }
}

// ---------------------------------------------------------------- K8: temporal proj + residual -> out (MFMA, coalesced)
__global__ __launch_bounds__(256) void k_proj_t_mfma(const bf16* __restrict__ AT,
        const bf16* __restrict__ Wb, const void* __restrict__ Bv,
        const bf16* __restrict__ x2, void* __restrict__ out,
        const int* __restrict__ flag, int m0){
  const bool f32in = flag[0] != 0;
  const int o0 = blockIdx.x * 128;
  const int tp = blockIdx.y;            // t-pair
  const int mg0 = blockIdx.z * 32;      // m base (32 | 576)
  const int tid = threadIdx.x, lane = tid & 63;
  const int wm = (tid >> 6) & 1, wn = tid >> 7;
  const int r15 = lane & 15, quad = lane >> 4;
  __shared__ bf16 As[128*72];
  __shared__ bf16 Bs[64*72];
  v4f acc[4][2];
  #pragma unroll
  for (int i = 0; i < 4; ++i)
    #pragma unroll
    for (int j = 0; j < 2; ++j) acc[i][j] = (v4f){0.f,0.f,0.f,0.f};
  for (int kc = 0; kc < 512; kc += 64){
    __syncthreads();
    #pragma unroll
    for (int r = 0; r < 8; ++r){
      int e4 = (tid + 256*r)*4;
      int row = e4 >> 6, k = e4 & 63;
      stage4b(&Wb[(size_t)(o0+row)*512 + kc + k], &As[row*72 + k]);
    }
    #pragma unroll
    for (int r = 0; r < 4; ++r){
      int e4 = (tid + 256*r)*4;
      int row = e4 >> 6, k = e4 & 63;
      stage4b(&AT[(size_t)(mg0 + (row & 31))*8192 + (tp*2 + (row >> 5))*512 + kc + k],
              &Bs[row*72 + k]);
    }
    __syncthreads();
    #pragma unroll
    for (int ks = 0; ks < 2; ++ks){
      v8s a[4], b[2];
      #pragma unroll
      for (int mi = 0; mi < 4; ++mi)
        a[mi] = *(const v8s*)&As[(wm*64 + mi*16 + r15)*72 + ks*32 + quad*8];
      #pragma unroll
      for (int ni = 0; ni < 2; ++ni)
        b[ni] = *(const v8s*)&Bs[(wn*32 + ni*16 + r15)*72 + ks*32 + quad*8];
      #pragma unroll
      for (int mi = 0; mi < 4; ++mi)
        #pragma unroll
        for (int ni = 0; ni < 2; ++ni)
          acc[mi][ni] = __builtin_amdgcn_mfma_f32_16x16x32_bf16(a[mi], b[ni], acc[mi][ni], 0, 0, 0);
    }
  }
  const int tt = tp*2 + wn;
  #pragma unroll
  for (int mi = 0; mi < 4; ++mi)
    #pragma unroll
    for (int rg = 0; rg < 4; ++rg){
      int o = o0 + wm*64 + mi*16 + quad*4 + rg;
      float bia = ldin(Bv, o, f32in);
      #pragma unroll
      for (int ni = 0; ni < 2; ++ni){
        int m = m0 + mg0 + ni*16 + r15;
        int b = m / 576, l = m - b*576;
        size_t addr = ((size_t)(b*512 + o)*16 + tt)*576 + l;
        float val = acc[mi][ni][rg] + bia + b2f(x2[addr]);
        if (f32in) ((float*)out)[addr] = val;
        else       ((bf16*)out)[addr] = f2b(val);
      }
    }
}

// ----------------------------------------------------------------
extern "C" void kernel_launch(void* const* d_in, const int* in_sizes, int n_in,
                              void* d_out, int out_size, void* d_ws, size_t ws_size,
                              hipStream_t stream){
  const void* x   = d_in[0];
  const void* nsw = d_in[1];
  const void* nsb = d_in[2];
  const void* qsw = d_in[3];
  const void* qsb = d_in[4];
  const void* psw = d_in[5];
  const void* psb = d_in[6];
  const void* ntw = d_in[7];
  const void* ntb = d_in[8];
  const void* qtw = d_in[9];
  const void* qtb = d_in[10];
  const void* ptw = d_in[11];
  const void* ptb = d_in[12];
  const void* rpk = d_in[13];
  const void* rpv = d_in[14];

  // Chunking and x2T gate from ws_size (constant across calls -> graph-safe).
  const size_t S_full = (size_t)32*294912;
  const size_t need_full = 256 + (S_full*5 + 9437184)*2;
  const size_t need_T    = 256 + (S_full*5 + (size_t)2*9437184)*2;  // +18.9 MB for x2T
  const int NCH = (ws_size >= need_full) ? 32 : 8;
  const int MCH = (NCH == 32) ? 1152 : 288;
  const size_t S = (size_t)NCH*294912;
  const int useT = (NCH == 32 && ws_size >= need_T) ? 1 : 0;

  int*  flag = (int*)d_ws;
  bf16* A  = (bf16*)((char*)d_ws + 256);   // S: xnT_s / xnT_t
  bf16* A2 = A  + S;                        // S: attT_s / attT_t (+ transient W copy)
  bf16* Bq = A2 + S;                        // 3S: qkv (+ transient proj_t W copy)
  bf16* Cx = Bq + 3*S;                      // 9,437,184: x2 residual
  bf16* Cx2 = Cx + 9437184;                 // 9,437,184: x2T [m][t][c] (if useT)
  const size_t kOff = S, vOff = 2*S;
  bf16* Wcv  = A2;
  bf16* Wcv2 = Bq;

  k_detect<<<1, 64, 0, stream>>>(x, flag);

  for (int n0 = 0; n0 < 32; n0 += NCH){
    k_gn_s       <<<dim3(32, NCH),   256, 0, stream>>>(x, nsw, nsb, A, flag, n0);
    k_cvtw       <<<dim3(768),       256, 0, stream>>>(qsw, Wcv, 196608, flag);
    k_qkv_s_mfma <<<dim3(108*NCH),   256, 0, stream>>>(A, Wcv, qsb, Bq, flag, kOff, vOff);
    k_attn_s_mfma<<<dim3(72*NCH),    256, 0, stream>>>(Bq, A2, kOff, vOff);
    k_proj_s_mfma<<<dim3(4, 9, NCH), 256, 0, stream>>>(A2, psw, psb, x, Cx, Cx2, useT, flag, n0);
  }
  for (int m0 = 0; m0 < 1152; m0 += MCH){
    if (useT) k_gn_t2<<<dim3(MCH),   256, 0, stream>>>(Cx2, ntw, ntb, A, flag, m0);
    else      k_gn_t <<<dim3(MCH),   256, 0, stream>>>(Cx,  ntw, ntb, A, flag, m0);
    k_cvtw       <<<dim3(768),       256, 0, stream>>>(qtw, Wcv, 196608, flag);
    k_qkv_t_mfma <<<dim3(3*MCH),     256, 0, stream>>>(A, Wcv, qtb, Bq, flag);
    k_attn_t     <<<dim3(8, MCH),    256, 0, stream>>>(Bq, rpk, rpv, A2, flag);
    k_cvtw       <<<dim3(256),       256, 0, stream>>>(ptw, Wcv2, 65536, flag);
    k_proj_t_mfma<<<dim3(4, 8, MCH/32), 256, 0, stream>>>(A2, Wcv2, ptb, Cx, d_out, flag, m0);
  }
}

// Round 2
// 536.474 us; speedup vs baseline: 1.1082x; 1.1082x over previous
//
#include <hip/hip_runtime.h>
#include <hip/hip_bf16.h>

typedef __hip_bfloat16 bf16;
typedef __attribute__((ext_vector_type(8))) short v8s;
typedef __attribute__((ext_vector_type(4))) float v4f;

__device__ __forceinline__ float b2f(bf16 v){ return __bfloat162float(v); }
__device__ __forceinline__ bf16  f2b(float v){ return __float2bfloat16(v); }

// Inputs may be bf16 OR f32 — runtime-detected flag (1 => f32). Output dtype follows.
__device__ __forceinline__ float ldin(const void* p, int i, bool f32in){
  return f32in ? ((const float*)p)[i] : b2f(((const bf16*)p)[i]);
}

// stage 4 consecutive source elems (f32-or-bf16) into dst as bf16 (8B write)
__device__ __forceinline__ void stage4(const void* src, size_t off, bool f32in, bf16* dst){
  union { bf16 h[4]; ushort4 u; } tmp;
  if (f32in){
    float4 f = *(const float4*)((const float*)src + off);
    tmp.h[0] = f2b(f.x); tmp.h[1] = f2b(f.y); tmp.h[2] = f2b(f.z); tmp.h[3] = f2b(f.w);
  } else {
    tmp.u = *(const ushort4*)((const ushort*)src + off);
  }
  *(ushort4*)dst = tmp.u;
}
__device__ __forceinline__ void stage4b(const bf16* src, bf16* dst){
  *(ushort4*)dst = *(const ushort4*)src;
}

// Problem: B=2, C=512, T=16, H=W=24, heads=8, ch=64
// ws: flag | A (S) | A2 (S) | Bq (3S) | Cx 9,437,184 | [Cx2 9,437,184 if room]
// Cx2 = x2 in [m][t][c] layout so gn_t reads coalesced.
// R1: proj_s epilogue was request-bound (WRITE_SIZE 130MB vs 38MB logical,
// MfmaUtil 3.7%, 100us) -> LDS-transpose epilogue with coalesced 16B stores.

// ---------------------------------------------------------------- detect input dtype
__global__ void k_detect(const void* x, int* flag){
  int tid = threadIdx.x;
  const bf16* p = (const bf16*)x;
  int cnt = 0;
  for (int i = tid; i < 512; i += 64){
    float v = b2f(p[i]);
    if (!(fabsf(v) <= 64.f)) cnt++;
  }
  #pragma unroll
  for (int off = 32; off; off >>= 1) cnt += __shfl_down(cnt, off, 64);
  if (tid == 0) flag[0] = (cnt > 16) ? 1 : 0;
}

// ---------------------------------------------------------------- weight convert -> bf16 scratch
__global__ __launch_bounds__(256) void k_cvtw(const void* __restrict__ W,
        bf16* __restrict__ out, int n4, const int* __restrict__ flag){
  const bool f32in = flag[0] != 0;
  int i = blockIdx.x*256 + threadIdx.x;
  if (i < n4) stage4(W, (size_t)i*4, f32in, out + (size_t)i*4);
}

// ---------------------------------------------------------------- K1: spatial groupnorm -> xnT [l][c]
__global__ __launch_bounds__(256) void k_gn_s(const void* __restrict__ x,
        const void* __restrict__ gw, const void* __restrict__ gb,
        bf16* __restrict__ xnT, const int* __restrict__ flag, int n0){
  const bool f32in = flag[0] != 0;
  const int g = blockIdx.x;
  const int nl = blockIdx.y;
  const int n = n0 + nl;
  const int b = n >> 4, t = n & 15;
  const int tid = threadIdx.x;
  __shared__ float xs[576*17];     // [l][cg] padded
  __shared__ float red[4][2];
  __shared__ float stats[2];
  float s = 0.f, q = 0.f;
  for (int i = tid; i < 9216; i += 256){
    int cg = i / 576, l = i - cg*576;
    int c = g*16 + cg;
    float v = ldin(x, ((b*512 + c)*16 + t)*576 + l, f32in);
    xs[l*17 + cg] = v; s += v; q += v*v;
  }
  #pragma unroll
  for (int off = 32; off; off >>= 1){ s += __shfl_down(s, off, 64); q += __shfl_down(q, off, 64); }
  int wid = tid >> 6;
  if ((tid & 63) == 0){ red[wid][0] = s; red[wid][1] = q; }
  __syncthreads();
  if (tid == 0){
    float S = red[0][0]+red[1][0]+red[2][0]+red[3][0];
    float Q = red[0][1]+red[1][1]+red[2][1]+red[3][1];
    float mean = S * (1.f/9216.f);
    float var  = Q * (1.f/9216.f) - mean*mean;
    stats[0] = mean; stats[1] = rsqrtf(fmaxf(var, 0.f) + 1e-5f);
  }
  __syncthreads();
  float mean = stats[0], rstd = stats[1];
  for (int i = tid; i < 9216; i += 256){
    int l = i >> 4, cg = i & 15;
    int c = g*16 + cg;
    xnT[(size_t)(nl*576 + l)*512 + c] =
        f2b((xs[l*17 + cg] - mean)*rstd*ldin(gw, c, f32in) + ldin(gb, c, f32in));
  }
}

// ---------------------------------------------------------------- K2: spatial qkv GEMM (MFMA, XCD-swizzled)
__global__ __launch_bounds__(256) void k_qkv_s_mfma(const bf16* __restrict__ XT,
        const bf16* __restrict__ Wb, const void* __restrict__ Bv,
        bf16* __restrict__ Y, const int* __restrict__ flag,
        size_t kOff, size_t vOff){
  const bool f32in = flag[0] != 0;
  const int bid = blockIdx.x;
  const int xcd = bid & 7, slot = bid >> 3;
  const int grp_local = slot / 12, oi = slot - grp_local*12;
  const int group = xcd + 8*grp_local;      // 0..9*NCH-1
  const int nl = group / 9;
  const int l0 = (group - nl*9) * 64;
  const int o0 = oi * 128;
  const int tid = threadIdx.x, lane = tid & 63;
  const int wm = (tid >> 6) & 1, wn = tid >> 7;
  const int r15 = lane & 15, quad = lane >> 4;
  __shared__ bf16 As[64*72];
  __shared__ bf16 Bs[128*72];
  v4f acc[2][4];
  #pragma unroll
  for (int i = 0; i < 2; ++i)
    #pragma unroll
    for (int j = 0; j < 4; ++j) acc[i][j] = (v4f){0.f,0.f,0.f,0.f};
  for (int kc = 0; kc < 512; kc += 64){
    __syncthreads();
    #pragma unroll
    for (int r = 0; r < 4; ++r){
      int e4 = (tid + 256*r)*4;
      int row = e4 >> 6, k = e4 & 63;
      stage4b(&XT[(size_t)(nl*576 + l0 + row)*512 + kc + k], &As[row*72 + k]);
    }
    #pragma unroll
    for (int r = 0; r < 8; ++r){
      int e4 = (tid + 256*r)*4;
      int row = e4 >> 6, k = e4 & 63;
      stage4b(&Wb[(size_t)(o0+row)*512 + kc + k], &Bs[row*72 + k]);
    }
    __syncthreads();
    #pragma unroll
    for (int ks = 0; ks < 2; ++ks){
      v8s a[2], b[4];
      #pragma unroll
      for (int mi = 0; mi < 2; ++mi)
        a[mi] = *(const v8s*)&As[(wm*32 + mi*16 + r15)*72 + ks*32 + quad*8];
      #pragma unroll
      for (int ni = 0; ni < 4; ++ni)
        b[ni] = *(const v8s*)&Bs[(wn*64 + ni*16 + r15)*72 + ks*32 + quad*8];
      #pragma unroll
      for (int mi = 0; mi < 2; ++mi)
        #pragma unroll
        for (int ni = 0; ni < 4; ++ni)
          acc[mi][ni] = __builtin_amdgcn_mfma_f32_16x16x32_bf16(a[mi], b[ni], acc[mi][ni], 0, 0, 0);
    }
  }
  const int seg = o0 >> 9;  // 0=Q,1=K,2=V
  size_t segbase = ((seg==0) ? 0 : (seg==1) ? kOff : vOff) + (size_t)nl*294912;
  const int ob = o0 & 511;
  #pragma unroll
  for (int mi = 0; mi < 2; ++mi)
    #pragma unroll
    for (int ni = 0; ni < 4; ++ni){
      int oseg = ob + wn*64 + ni*16 + r15;
      float bia = ldin(Bv, o0 + wn*64 + ni*16 + r15, f32in);
      #pragma unroll
      for (int rg = 0; rg < 4; ++rg){
        int l = l0 + wm*32 + mi*16 + quad*4 + rg;
        float val = acc[mi][ni][rg] + bia;
        size_t dst = (seg==2) ? segbase + (size_t)oseg*576 + l
                              : segbase + (size_t)l*512 + oseg;
        Y[dst] = f2b(val);
      }
    }
}

// ---------------------------------------------------------------- K3: spatial attention (flash MFMA) -> attT [l][c]
__global__ __launch_bounds__(256, 4) void k_attn_s_mfma(const bf16* __restrict__ qkv,
        bf16* __restrict__ attT, size_t kOff, size_t vOff){
  const int bid = blockIdx.x;
  const int xcd = bid & 7, slot = bid >> 3;
  const int nl = xcd + 8*(slot/72);
  const int idx = slot - 72*(slot/72);
  const int head = idx/9, t0 = idx - 9*head;
  const int tid = threadIdx.x, lane = tid & 63, w = tid >> 6;
  const int r15 = lane & 15, quad = lane >> 4;
  __shared__ bf16 Ks[64*72];
  __shared__ bf16 Vs[64*72];
  __shared__ bf16 Ps[4][16*72];
  const bf16* QT = qkv + (size_t)nl*294912;
  const bf16* KT = qkv + kOff + (size_t)nl*294912;
  const bf16* Vp = qkv + vOff + (size_t)nl*294912;
  const int c0 = head*64;
  v8s aq0, aq1;
  {
    const bf16* qrow = QT + (size_t)(t0*64 + w*16 + r15)*512 + c0;
    aq0 = *(const v8s*)(qrow + quad*8);
    aq1 = *(const v8s*)(qrow + 32 + quad*8);
  }
  v4f oc[4];
  #pragma unroll
  for (int ni = 0; ni < 4; ++ni) oc[ni] = (v4f){0.f,0.f,0.f,0.f};
  float m_run[4] = {-1e30f,-1e30f,-1e30f,-1e30f};
  float l_run[4] = {0.f,0.f,0.f,0.f};
  for (int sc = 0; sc < 9; ++sc){
    __syncthreads();
    #pragma unroll
    for (int r = 0; r < 4; ++r){
      int e4 = (tid + 256*r)*4;
      int row = e4 >> 6, col = e4 & 63;
      stage4b(&KT[(size_t)(sc*64 + row)*512 + c0 + col], &Ks[row*72 + col]);
      stage4b(&Vp[(size_t)(c0 + row)*576 + sc*64 + col], &Vs[row*72 + col]);
    }
    __syncthreads();
    v4f sa[4];
    #pragma unroll
    for (int sj = 0; sj < 4; ++sj) sa[sj] = (v4f){0.f,0.f,0.f,0.f};
    #pragma unroll
    for (int sj = 0; sj < 4; ++sj){
      v8s b0 = *(const v8s*)&Ks[(sj*16 + r15)*72 + quad*8];
      v8s b1 = *(const v8s*)&Ks[(sj*16 + r15)*72 + 32 + quad*8];
      sa[sj] = __builtin_amdgcn_mfma_f32_16x16x32_bf16(aq0, b0, sa[sj], 0, 0, 0);
      sa[sj] = __builtin_amdgcn_mfma_f32_16x16x32_bf16(aq1, b1, sa[sj], 0, 0, 0);
    }
    float cmx[4] = {-1e30f,-1e30f,-1e30f,-1e30f};
    #pragma unroll
    for (int sj = 0; sj < 4; ++sj)
      #pragma unroll
      for (int rg = 0; rg < 4; ++rg){
        float v = sa[sj][rg]*0.125f;
        sa[sj][rg] = v;
        cmx[rg] = fmaxf(cmx[rg], v);
      }
    #pragma unroll
    for (int off = 1; off < 16; off <<= 1)
      #pragma unroll
      for (int rg = 0; rg < 4; ++rg) cmx[rg] = fmaxf(cmx[rg], __shfl_xor(cmx[rg], off, 64));
    float alpha[4];
    #pragma unroll
    for (int rg = 0; rg < 4; ++rg){
      float mnew = fmaxf(m_run[rg], cmx[rg]);
      alpha[rg] = __expf(m_run[rg] - mnew);
      m_run[rg] = mnew;
    }
    float psum[4] = {0.f,0.f,0.f,0.f};
    #pragma unroll
    for (int sj = 0; sj < 4; ++sj)
      #pragma unroll
      for (int rg = 0; rg < 4; ++rg){
        float e = __expf(sa[sj][rg] - m_run[rg]);
        sa[sj][rg] = e; psum[rg] += e;
      }
    #pragma unroll
    for (int off = 1; off < 16; off <<= 1)
      #pragma unroll
      for (int rg = 0; rg < 4; ++rg) psum[rg] += __shfl_xor(psum[rg], off, 64);
    #pragma unroll
    for (int rg = 0; rg < 4; ++rg) l_run[rg] = l_run[rg]*alpha[rg] + psum[rg];
    #pragma unroll
    for (int ni = 0; ni < 4; ++ni)
      #pragma unroll
      for (int rg = 0; rg < 4; ++rg) oc[ni][rg] *= alpha[rg];
    #pragma unroll
    for (int sj = 0; sj < 4; ++sj)
      #pragma unroll
      for (int rg = 0; rg < 4; ++rg)
        Ps[w][(quad*4 + rg)*72 + sj*16 + r15] = f2b(sa[sj][rg]);
    #pragma unroll
    for (int ks = 0; ks < 2; ++ks){
      v8s a = *(const v8s*)&Ps[w][r15*72 + ks*32 + quad*8];
      #pragma unroll
      for (int ni = 0; ni < 4; ++ni){
        v8s b = *(const v8s*)&Vs[(ni*16 + r15)*72 + ks*32 + quad*8];
        oc[ni] = __builtin_amdgcn_mfma_f32_16x16x32_bf16(a, b, oc[ni], 0, 0, 0);
      }
    }
  }
  float inv[4];
  #pragma unroll
  for (int rg = 0; rg < 4; ++rg) inv[rg] = 1.f / l_run[rg];
  #pragma unroll
  for (int ni = 0; ni < 4; ++ni)
    #pragma unroll
    for (int rg = 0; rg < 4; ++rg){
      int t = t0*64 + w*16 + quad*4 + rg;
      attT[(size_t)(nl*576 + t)*512 + c0 + ni*16 + r15] = f2b(oc[ni][rg]*inv[rg]);
    }
}

// ---------------------------------------------------------------- K4: spatial proj + residual (MFMA)
// R1 rewrite: LDS-transpose epilogue. Stage acc+bias into As tile [128 o][72],
// phase 1 adds residual with coalesced float4 reads + 16B x2 stores, phase 2
// writes x2T [m][t][c] with 16B coalesced stores. Wb is pre-converted bf16.
__global__ __launch_bounds__(256) void k_proj_s_mfma(const bf16* __restrict__ AT,
        const bf16* __restrict__ Wb, const void* __restrict__ Bv,
        const void* __restrict__ xin, bf16* __restrict__ x2,
        bf16* __restrict__ x2T, int doT,
        const int* __restrict__ flag, int n0){
  const bool f32in = flag[0] != 0;
  const int o0 = blockIdx.x * 128;
  const int l0 = blockIdx.y * 64;
  const int nl = blockIdx.z;
  const int n = n0 + nl;
  const int b = n >> 4, t = n & 15;
  const int tid = threadIdx.x, lane = tid & 63;
  const int wm = (tid >> 6) & 1, wn = tid >> 7;
  const int r15 = lane & 15, quad = lane >> 4;
  __shared__ bf16 As[128*72];
  __shared__ bf16 Bs[64*72];
  v4f acc[4][2];
  #pragma unroll
  for (int i = 0; i < 4; ++i)
    #pragma unroll
    for (int j = 0; j < 2; ++j) acc[i][j] = (v4f){0.f,0.f,0.f,0.f};
  for (int kc = 0; kc < 512; kc += 64){
    __syncthreads();
    #pragma unroll
    for (int r = 0; r < 8; ++r){
      int e4 = (tid + 256*r)*4;
      int row = e4 >> 6, k = e4 & 63;
      stage4b(&Wb[(size_t)(o0+row)*512 + kc + k], &As[row*72 + k]);
    }
    #pragma unroll
    for (int r = 0; r < 4; ++r){
      int e4 = (tid + 256*r)*4;
      int row = e4 >> 6, k = e4 & 63;
      stage4b(&AT[(size_t)(nl*576 + l0 + row)*512 + kc + k], &Bs[row*72 + k]);
    }
    __syncthreads();
    #pragma unroll
    for (int ks = 0; ks < 2; ++ks){
      v8s a[4], b[2];
      #pragma unroll
      for (int mi = 0; mi < 4; ++mi)
        a[mi] = *(const v8s*)&As[(wm*64 + mi*16 + r15)*72 + ks*32 + quad*8];
      #pragma unroll
      for (int ni = 0; ni < 2; ++ni)
        b[ni] = *(const v8s*)&Bs[(wn*32 + ni*16 + r15)*72 + ks*32 + quad*8];
      #pragma unroll
      for (int mi = 0; mi < 4; ++mi)
        #pragma unroll
        for (int ni = 0; ni < 2; ++ni)
          acc[mi][ni] = __builtin_amdgcn_mfma_f32_16x16x32_bf16(a[mi], b[ni], acc[mi][ni], 0, 0, 0);
    }
  }
  // -------- epilogue: stage acc+bias into As as [o_rel][l_rel] (stride 72)
  __syncthreads();
  #pragma unroll
  for (int mi = 0; mi < 4; ++mi){
    int orel = wm*64 + mi*16 + quad*4;
    #pragma unroll
    for (int rg = 0; rg < 4; ++rg){
      float bia = ldin(Bv, o0 + orel + rg, f32in);
      #pragma unroll
      for (int ni = 0; ni < 2; ++ni)
        As[(orel + rg)*72 + wn*32 + ni*16 + r15] = f2b(acc[mi][ni][rg] + bia);
    }
  }
  __syncthreads();
  // phase 1: residual add + coalesced x2 write (+writeback for phase 2)
  const size_t xrow = ((size_t)(b*512 + o0)*16 + t)*576 + l0;
  for (int it = 0; it < 4; ++it){
    int idx = tid + it*256;             // 1024 chunks of 8 elems
    int o = idx >> 3, lc = (idx & 7)*8;
    union { bf16 h[8]; v8s v; } val;
    val.v = *(const v8s*)&As[o*72 + lc];
    size_t ga = xrow + (size_t)o*9216 + lc;
    if (f32in){
      const float* xp = (const float*)xin + ga;
      float4 f0 = *(const float4*)xp;
      float4 f1 = *(const float4*)(xp + 4);
      val.h[0] = f2b(b2f(val.h[0]) + f0.x);
      val.h[1] = f2b(b2f(val.h[1]) + f0.y);
      val.h[2] = f2b(b2f(val.h[2]) + f0.z);
      val.h[3] = f2b(b2f(val.h[3]) + f0.w);
      val.h[4] = f2b(b2f(val.h[4]) + f1.x);
      val.h[5] = f2b(b2f(val.h[5]) + f1.y);
      val.h[6] = f2b(b2f(val.h[6]) + f1.z);
      val.h[7] = f2b(b2f(val.h[7]) + f1.w);
    } else {
      union { bf16 h[8]; v8s v; } xv;
      xv.v = *(const v8s*)((const bf16*)xin + ga);
      #pragma unroll
      for (int j = 0; j < 8; ++j) val.h[j] = f2b(b2f(val.h[j]) + b2f(xv.h[j]));
    }
    *(v8s*)&x2[ga] = val.v;
    if (doT) *(v8s*)&As[o*72 + lc] = val.v;
  }
  if (doT){
    __syncthreads();
    // phase 2: x2T [m][t][c]: per chunk, 8 consecutive o at fixed l
    const size_t tbase = ((size_t)b*576 + l0)*8192 + (size_t)t*512 + o0;
    for (int it = 0; it < 4; ++it){
      int l = (tid & 15) + it*16;
      int ocg = (tid >> 4)*8;
      union { bf16 h[8]; v8s v; } val;
      #pragma unroll
      for (int j = 0; j < 8; ++j) val.h[j] = As[(ocg + j)*72 + l];
      *(v8s*)&x2T[tbase + (size_t)l*8192 + ocg] = val.v;
    }
  }
}

// ---------------------------------------------------------------- K5a: temporal groupnorm (scattered x2) -> xnT [m][t][c]
__global__ __launch_bounds__(256) void k_gn_t(const bf16* __restrict__ x2,
        const void* __restrict__ gw, const void* __restrict__ gb,
        bf16* __restrict__ xnT, const int* __restrict__ flag, int m0){
  const bool f32in = flag[0] != 0;
  const int ml = blockIdx.x;
  const int m = m0 + ml;
  const int b = m / 576, l = m - b*576;
  const int tid = threadIdx.x;
  __shared__ float xs[8192];
  __shared__ float mg[32], rg[32];
  for (int i = tid; i < 8192; i += 256){
    int t = i >> 9, c = i & 511;
    xs[i] = b2f(x2[((b*512 + c)*16 + t)*576 + l]);
  }
  __syncthreads();
  {
    int g = tid >> 3, ii = tid & 7;
    float s = 0.f, q = 0.f;
    for (int idx = ii; idx < 256; idx += 8){
      int t = idx >> 4, cg = idx & 15;
      float v = xs[t*512 + g*16 + cg]; s += v; q += v*v;
    }
    #pragma unroll
    for (int off = 1; off < 8; off <<= 1){ s += __shfl_xor(s, off, 64); q += __shfl_xor(q, off, 64); }
    if (ii == 0){
      float mean = s*(1.f/256.f);
      float var  = q*(1.f/256.f) - mean*mean;
      mg[g] = mean; rg[g] = rsqrtf(fmaxf(var, 0.f) + 1e-5f);
    }
  }
  __syncthreads();
  for (int i = tid; i < 8192; i += 256){
    int c = i & 511, g = c >> 4;
    xnT[(size_t)ml*8192 + i] = f2b((xs[i] - mg[g])*rg[g]*ldin(gw, c, f32in) + ldin(gb, c, f32in));
  }
}

// ---------------------------------------------------------------- K5b: temporal groupnorm (coalesced x2T)
__global__ __launch_bounds__(256) void k_gn_t2(const bf16* __restrict__ x2T,
        const void* __restrict__ gw, const void* __restrict__ gb,
        bf16* __restrict__ xnT, const int* __restrict__ flag, int m0){
  const bool f32in = flag[0] != 0;
  const int ml = blockIdx.x;
  const int m = m0 + ml;
  const int tid = threadIdx.x;
  __shared__ float xs[8192];
  __shared__ float mg[32], rg[32];
  for (int i = tid; i < 8192; i += 256)
    xs[i] = b2f(x2T[(size_t)m*8192 + i]);     // [t][c] order, fully coalesced
  __syncthreads();
  {
    int g = tid >> 3, ii = tid & 7;
    float s = 0.f, q = 0.f;
    for (int idx = ii; idx < 256; idx += 8){
      int t = idx >> 4, cg = idx & 15;
      float v = xs[t*512 + g*16 + cg]; s += v; q += v*v;
    }
    #pragma unroll
    for (int off = 1; off < 8; off <<= 1){ s += __shfl_xor(s, off, 64); q += __shfl_xor(q, off, 64); }
    if (ii == 0){
      float mean = s*(1.f/256.f);
      float var  = q*(1.f/256.f) - mean*mean;
      mg[g] = mean; rg[g] = rsqrtf(fmaxf(var, 0.f) + 1e-5f);
    }
  }
  __syncthreads();
  for (int i = tid; i < 8192; i += 256){
    int c = i & 511, g = c >> 4;
    xnT[(size_t)ml*8192 + i] = f2b((xs[i] - mg[g])*rg[g]*ldin(gw, c, f32in) + ldin(gb, c, f32in));
  }
}

// ---------------------------------------------------------------- K6: temporal qkv GEMM (MFMA, XCD-swizzled, 4 m per block)
__global__ __launch_bounds__(256) void k_qkv_t_mfma(const bf16* __restrict__ XT,
        const bf16* __restrict__ Wb, const void* __restrict__ Bv,
        bf16* __restrict__ Y, const int* __restrict__ flag){
  const bool f32in = flag[0] != 0;
  const int bid = blockIdx.x;
  const int xcd = bid & 7, slot = bid >> 3;
  const int grp_local = slot / 12, oi = slot - grp_local*12;
  const int mg0 = (xcd + 8*grp_local) * 4;
  const int o0 = oi * 128;
  const int tid = threadIdx.x, lane = tid & 63;
  const int wm = (tid >> 6) & 1, wn = tid >> 7;
  const int r15 = lane & 15, quad = lane >> 4;
  __shared__ bf16 As[128*72];
  __shared__ bf16 Bs[64*72];
  v4f acc[4][2];
  #pragma unroll
  for (int i = 0; i < 4; ++i)
    #pragma unroll
    for (int j = 0; j < 2; ++j) acc[i][j] = (v4f){0.f,0.f,0.f,0.f};
  for (int kc = 0; kc < 512; kc += 64){
    __syncthreads();
    #pragma unroll
    for (int r = 0; r < 8; ++r){
      int e4 = (tid + 256*r)*4;
      int row = e4 >> 6, k = e4 & 63;
      stage4b(&Wb[(size_t)(o0+row)*512 + kc + k], &As[row*72 + k]);
    }
    #pragma unroll
    for (int r = 0; r < 4; ++r){
      int e4 = (tid + 256*r)*4;
      int row = e4 >> 6, k = e4 & 63;
      stage4b(&XT[(size_t)(mg0 + (row >> 4))*8192 + (row & 15)*512 + kc + k], &Bs[row*72 + k]);
    }
    __syncthreads();
    #pragma unroll
    for (int ks = 0; ks < 2; ++ks){
      v8s a[4], b[2];
      #pragma unroll
      for (int mi = 0; mi < 4; ++mi)
        a[mi] = *(const v8s*)&As[(wm*64 + mi*16 + r15)*72 + ks*32 + quad*8];
      #pragma unroll
      for (int ni = 0; ni < 2; ++ni)
        b[ni] = *(const v8s*)&Bs[(wn*32 + ni*16 + r15)*72 + ks*32 + quad*8];
      #pragma unroll
      for (int mi = 0; mi < 4; ++mi)
        #pragma unroll
        for (int ni = 0; ni < 2; ++ni)
          acc[mi][ni] = __builtin_amdgcn_mfma_f32_16x16x32_bf16(a[mi], b[ni], acc[mi][ni], 0, 0, 0);
    }
  }
  #pragma unroll
  for (int mi = 0; mi < 4; ++mi)
    #pragma unroll
    for (int rg = 0; rg < 4; ++rg){
      int o = o0 + wm*64 + mi*16 + quad*4 + rg;
      float bia = ldin(Bv, o, f32in);
      #pragma unroll
      for (int ni = 0; ni < 2; ++ni){
        int nidx = wn*32 + ni*16 + r15;
        int mb = nidx >> 4, t = nidx & 15;
        Y[((size_t)(mg0 + mb)*1536 + o)*16 + t] = f2b(acc[mi][ni][rg] + bia);
      }
    }
}

// ---------------------------------------------------------------- K7: temporal attention -> attT [m][t][c]
__global__ __launch_bounds__(256) void k_attn_t(const bf16* __restrict__ qkv,
        const void* __restrict__ tbk, const void* __restrict__ tbv,
        bf16* __restrict__ attT, const int* __restrict__ flag){
  const bool f32in = flag[0] != 0;
  const int head = blockIdx.x;
  const int ml = blockIdx.y;
  const int tid = threadIdx.x;
  __shared__ float qsT[16*68], ksT[16*68], vsT[16*68];  // [t][c], stride 68 (16B-aligned rows)
  __shared__ float tks[33*68], tvs[33*68];              // [d][c]
  __shared__ float ps[16*17];
  const int base = (ml*1536 + head*64)*16;
  for (int i = tid; i < 1024; i += 256){
    int c = i >> 4, t = i & 15;
    qsT[t*68 + c] = b2f(qkv[base + i]);
    ksT[t*68 + c] = b2f(qkv[base + 8192 + i]);
    vsT[t*68 + c] = b2f(qkv[base + 16384 + i]);
  }
  for (int i = tid; i < 33*64; i += 256){
    int d = i >> 6, c = i & 63;
    tks[d*68 + c] = ldin(tbk, i, f32in);
    tvs[d*68 + c] = ldin(tbv, i, f32in);
  }
  __syncthreads();
  {
    const int t = tid >> 4, s = tid & 15;
    const float4* qt = (const float4*)&qsT[t*68];
    const float4* kr = (const float4*)&ksT[s*68];
    const float4* q2 = (const float4*)&qsT[s*68];
    const float4* tr = (const float4*)&tks[(t - s + 16)*68];
    float qk = 0.f, rp = 0.f;
    #pragma unroll
    for (int c4 = 0; c4 < 16; ++c4){
      float4 a = qt[c4], b = kr[c4];
      qk += a.x*b.x + a.y*b.y + a.z*b.z + a.w*b.w;
      float4 a2 = q2[c4], tb = tr[c4];
      rp += a2.x*tb.x + a2.y*tb.y + a2.z*tb.z + a2.w*tb.w;
    }
    float logit = 0.125f*qk + 0.35355339059327373f*rp;
    if (s > t) logit = -1e8f;
    float mx = logit;
    #pragma unroll
    for (int off = 8; off; off >>= 1) mx = fmaxf(mx, __shfl_xor(mx, off, 16));
    float e = __expf(logit - mx);
    float tot = e;
    #pragma unroll
    for (int off = 8; off; off >>= 1) tot += __shfl_xor(tot, off, 16);
    ps[t*17 + s] = e / tot;
  }
  __syncthreads();
  {
    const int c4 = tid & 15, t = tid >> 4;
    float4 acc = {0.f,0.f,0.f,0.f};
    #pragma unroll
    for (int s = 0; s < 16; ++s){
      float p = ps[t*17 + s];
      float4 v4 = *(const float4*)&vsT[s*68 + c4*4];
      float4 t4 = *(const float4*)&tvs[(s - t + 16)*68 + c4*4];
      acc.x += p*(v4.x + t4.x); acc.y += p*(v4.y + t4.y);
      acc.z += p*(v4.z + t4.z); acc.w += p*(v4.w + t4.w);
    }
    union { bf16 h[4]; ushort4 u; } o;
    o.h[0] = f2b(acc.x); o.h[1] = f2b(acc.y); o.h[2] = f2b(acc.z); o.h[3] = f2b(acc.w);
    *(ushort4*)&attT[(size_t)ml*8192 + t*512 + head*64 + c4*4] = o.u;
  }
}

// ---------------------------------------------------------------- K8: temporal proj + residual -> out (MFMA, coalesced)
__global__ __launch_bounds__(256) void k_proj_t_mfma(const bf16* __restrict__ AT,
        const bf16* __restrict__ Wb, const void* __restrict__ Bv,
        const bf16* __restrict__ x2, void* __restrict__ out,
        const int* __restrict__ flag, int m0){
  const bool f32in = flag[0] != 0;
  const int o0 = blockIdx.x * 128;
  const int tp = blockIdx.y;            // t-pair
  const int mg0 = blockIdx.z * 32;      // m base (32 | 576)
  const int tid = threadIdx.x, lane = tid & 63;
  const int wm = (tid >> 6) & 1, wn = tid >> 7;
  const int r15 = lane & 15, quad = lane >> 4;
  __shared__ bf16 As[128*72];
  __shared__ bf16 Bs[64*72];
  v4f acc[4][2];
  #pragma unroll
  for (int i = 0; i < 4; ++i)
    #pragma unroll
    for (int j = 0; j < 2; ++j) acc[i][j] = (v4f){0.f,0.f,0.f,0.f};
  for (int kc = 0; kc < 512; kc += 64){
    __syncthreads();
    #pragma unroll
    for (int r = 0; r < 8; ++r){
      int e4 = (tid + 256*r)*4;
      int row = e4 >> 6, k = e4 & 63;
      stage4b(&Wb[(size_t)(o0+row)*512 + kc + k], &As[row*72 + k]);
    }
    #pragma unroll
    for (int r = 0; r < 4; ++r){
      int e4 = (tid + 256*r)*4;
      int row = e4 >> 6, k = e4 & 63;
      stage4b(&AT[(size_t)(mg0 + (row & 31))*8192 + (tp*2 + (row >> 5))*512 + kc + k],
              &Bs[row*72 + k]);
    }
    __syncthreads();
    #pragma unroll
    for (int ks = 0; ks < 2; ++ks){
      v8s a[4], b[2];
      #pragma unroll
      for (int mi = 0; mi < 4; ++mi)
        a[mi] = *(const v8s*)&As[(wm*64 + mi*16 + r15)*72 + ks*32 + quad*8];
      #pragma unroll
      for (int ni = 0; ni < 2; ++ni)
        b[ni] = *(const v8s*)&Bs[(wn*32 + ni*16 + r15)*72 + ks*32 + quad*8];
      #pragma unroll
      for (int mi = 0; mi < 4; ++mi)
        #pragma unroll
        for (int ni = 0; ni < 2; ++ni)
          acc[mi][ni] = __builtin_amdgcn_mfma_f32_16x16x32_bf16(a[mi], b[ni], acc[mi][ni], 0, 0, 0);
    }
  }
  const int tt = tp*2 + wn;
  #pragma unroll
  for (int mi = 0; mi < 4; ++mi)
    #pragma unroll
    for (int rg = 0; rg < 4; ++rg){
      int o = o0 + wm*64 + mi*16 + quad*4 + rg;
      float bia = ldin(Bv, o, f32in);
      #pragma unroll
      for (int ni = 0; ni < 2; ++ni){
        int m = m0 + mg0 + ni*16 + r15;
        int b = m / 576, l = m - b*576;
        size_t addr = ((size_t)(b*512 + o)*16 + tt)*576 + l;
        float val = acc[mi][ni][rg] + bia + b2f(x2[addr]);
        if (f32in) ((float*)out)[addr] = val;
        else       ((bf16*)out)[addr] = f2b(val);
      }
    }
}

// ----------------------------------------------------------------
extern "C" void kernel_launch(void* const* d_in, const int* in_sizes, int n_in,
                              void* d_out, int out_size, void* d_ws, size_t ws_size,
                              hipStream_t stream){
  const void* x   = d_in[0];
  const void* nsw = d_in[1];
  const void* nsb = d_in[2];
  const void* qsw = d_in[3];
  const void* qsb = d_in[4];
  const void* psw = d_in[5];
  const void* psb = d_in[6];
  const void* ntw = d_in[7];
  const void* ntb = d_in[8];
  const void* qtw = d_in[9];
  const void* qtb = d_in[10];
  const void* ptw = d_in[11];
  const void* ptb = d_in[12];
  const void* rpk = d_in[13];
  const void* rpv = d_in[14];

  // Chunking and x2T gate from ws_size (constant across calls -> graph-safe).
  const size_t S_full = (size_t)32*294912;
  const size_t need_full = 256 + (S_full*5 + 9437184)*2;
  const size_t need_T    = 256 + (S_full*5 + (size_t)2*9437184)*2;  // +18.9 MB for x2T
  const int NCH = (ws_size >= need_full) ? 32 : 8;
  const int MCH = (NCH == 32) ? 1152 : 288;
  const size_t S = (size_t)NCH*294912;
  const int useT = (NCH == 32 && ws_size >= need_T) ? 1 : 0;

  int*  flag = (int*)d_ws;
  bf16* A  = (bf16*)((char*)d_ws + 256);   // S: xnT_s / xnT_t
  bf16* A2 = A  + S;                        // S: attT_s / attT_t (+ transient W copy)
  bf16* Bq = A2 + S;                        // 3S: qkv (+ transient W copies)
  bf16* Cx = Bq + 3*S;                      // 9,437,184: x2 residual
  bf16* Cx2 = Cx + 9437184;                 // 9,437,184: x2T [m][t][c] (if useT)
  const size_t kOff = S, vOff = 2*S;
  bf16* Wcv  = A2;
  bf16* Wcv2 = Bq;

  k_detect<<<1, 64, 0, stream>>>(x, flag);

  for (int n0 = 0; n0 < 32; n0 += NCH){
    k_gn_s       <<<dim3(32, NCH),   256, 0, stream>>>(x, nsw, nsb, A, flag, n0);
    k_cvtw       <<<dim3(768),       256, 0, stream>>>(qsw, Wcv, 196608, flag);
    k_qkv_s_mfma <<<dim3(108*NCH),   256, 0, stream>>>(A, Wcv, qsb, Bq, flag, kOff, vOff);
    k_attn_s_mfma<<<dim3(72*NCH),    256, 0, stream>>>(Bq, A2, kOff, vOff);
    // proj_s weight pre-convert into Bq (qkv dead after attn_s)
    k_cvtw       <<<dim3(256),       256, 0, stream>>>(psw, Bq, 65536, flag);
    k_proj_s_mfma<<<dim3(4, 9, NCH), 256, 0, stream>>>(A2, Bq, psb, x, Cx, Cx2, useT, flag, n0);
  }
  for (int m0 = 0; m0 < 1152; m0 += MCH){
    if (useT) k_gn_t2<<<dim3(MCH),   256, 0, stream>>>(Cx2, ntw, ntb, A, flag, m0);
    else      k_gn_t <<<dim3(MCH),   256, 0, stream>>>(Cx,  ntw, ntb, A, flag, m0);
    k_cvtw       <<<dim3(768),       256, 0, stream>>>(qtw, Wcv, 196608, flag);
    k_qkv_t_mfma <<<dim3(3*MCH),     256, 0, stream>>>(A, Wcv, qtb, Bq, flag);
    k_attn_t     <<<dim3(8, MCH),    256, 0, stream>>>(Bq, rpk, rpv, A2, flag);
    k_cvtw       <<<dim3(256),       256, 0, stream>>>(ptw, Wcv2, 65536, flag);
    k_proj_t_mfma<<<dim3(4, 8, MCH/32), 256, 0, stream>>>(A2, Wcv2, ptb, Cx, d_out, flag, m0);
  }
}

// Round 3
// 510.745 us; speedup vs baseline: 1.1640x; 1.0504x over previous
//
#include <hip/hip_runtime.h>
#include <hip/hip_bf16.h>

typedef __hip_bfloat16 bf16;
typedef __attribute__((ext_vector_type(8))) short v8s;
typedef __attribute__((ext_vector_type(4))) float v4f;

__device__ __forceinline__ float b2f(bf16 v){ return __bfloat162float(v); }
__device__ __forceinline__ bf16  f2b(float v){ return __float2bfloat16(v); }

// Inputs may be bf16 OR f32 — runtime-detected flag (1 => f32). Output dtype follows.
__device__ __forceinline__ float ldin(const void* p, int i, bool f32in){
  return f32in ? ((const float*)p)[i] : b2f(((const bf16*)p)[i]);
}

// stage 4 consecutive source elems (f32-or-bf16) into dst as bf16 (8B write)
__device__ __forceinline__ void stage4(const void* src, size_t off, bool f32in, bf16* dst){
  union { bf16 h[4]; ushort4 u; } tmp;
  if (f32in){
    float4 f = *(const float4*)((const float*)src + off);
    tmp.h[0] = f2b(f.x); tmp.h[1] = f2b(f.y); tmp.h[2] = f2b(f.z); tmp.h[3] = f2b(f.w);
  } else {
    tmp.u = *(const ushort4*)((const ushort*)src + off);
  }
  *(ushort4*)dst = tmp.u;
}
__device__ __forceinline__ void stage4b(const bf16* src, bf16* dst){
  *(ushort4*)dst = *(const ushort4*)src;
}

// async global->LDS, 16B per lane. LDS dest must be wave-uniform base (HW adds lane*16).
__device__ __forceinline__ void async_cp16(const bf16* g, bf16* l){
  __builtin_amdgcn_global_load_lds(
      (const __attribute__((address_space(1))) unsigned int*)g,
      (__attribute__((address_space(3))) unsigned int*)l, 16, 0, 0);
}

// Problem: B=2, C=512, T=16, H=W=24, heads=8, ch=64
// ws: flag | A (S) | A2 (S) | Bq (3S) | Cx 9,437,184 | [Cx2 9,437,184 if room]
// R1: proj_s epilogue was request-bound -> LDS-transpose epilogue (WIN, -58us).
// R2: qkv_s/qkv_t were latency-bound (MfmaUtil 12.5%, VALU 18.6%, HBM 10.6%,
//     324 TF) -> unified 128x128 m97-structure GEMM with global_load_lds.

// ---------------------------------------------------------------- detect input dtype
__global__ void k_detect(const void* x, int* flag){
  int tid = threadIdx.x;
  const bf16* p = (const bf16*)x;
  int cnt = 0;
  for (int i = tid; i < 512; i += 64){
    float v = b2f(p[i]);
    if (!(fabsf(v) <= 64.f)) cnt++;
  }
  #pragma unroll
  for (int off = 32; off; off >>= 1) cnt += __shfl_down(cnt, off, 64);
  if (tid == 0) flag[0] = (cnt > 16) ? 1 : 0;
}

// ---------------------------------------------------------------- weight convert -> bf16 scratch
__global__ __launch_bounds__(256) void k_cvtw(const void* __restrict__ W,
        bf16* __restrict__ out, int n4, const int* __restrict__ flag){
  const bool f32in = flag[0] != 0;
  int i = blockIdx.x*256 + threadIdx.x;
  if (i < n4) stage4(W, (size_t)i*4, f32in, out + (size_t)i*4);
}

// ---------------------------------------------------------------- K1: spatial groupnorm -> xnT [l][c]
__global__ __launch_bounds__(256) void k_gn_s(const void* __restrict__ x,
        const void* __restrict__ gw, const void* __restrict__ gb,
        bf16* __restrict__ xnT, const int* __restrict__ flag, int n0){
  const bool f32in = flag[0] != 0;
  const int g = blockIdx.x;
  const int nl = blockIdx.y;
  const int n = n0 + nl;
  const int b = n >> 4, t = n & 15;
  const int tid = threadIdx.x;
  __shared__ float xs[576*17];     // [l][cg] padded
  __shared__ float red[4][2];
  __shared__ float stats[2];
  float s = 0.f, q = 0.f;
  for (int i = tid; i < 9216; i += 256){
    int cg = i / 576, l = i - cg*576;
    int c = g*16 + cg;
    float v = ldin(x, ((b*512 + c)*16 + t)*576 + l, f32in);
    xs[l*17 + cg] = v; s += v; q += v*v;
  }
  #pragma unroll
  for (int off = 32; off; off >>= 1){ s += __shfl_down(s, off, 64); q += __shfl_down(q, off, 64); }
  int wid = tid >> 6;
  if ((tid & 63) == 0){ red[wid][0] = s; red[wid][1] = q; }
  __syncthreads();
  if (tid == 0){
    float S = red[0][0]+red[1][0]+red[2][0]+red[3][0];
    float Q = red[0][1]+red[1][1]+red[2][1]+red[3][1];
    float mean = S * (1.f/9216.f);
    float var  = Q * (1.f/9216.f) - mean*mean;
    stats[0] = mean; stats[1] = rsqrtf(fmaxf(var, 0.f) + 1e-5f);
  }
  __syncthreads();
  float mean = stats[0], rstd = stats[1];
  for (int i = tid; i < 9216; i += 256){
    int l = i >> 4, cg = i & 15;
    int c = g*16 + cg;
    xnT[(size_t)(nl*576 + l)*512 + c] =
        f2b((xs[l*17 + cg] - mean)*rstd*ldin(gw, c, f32in) + ldin(gb, c, f32in));
  }
}

// ---------------------------------------------------------------- K2/K6: unified qkv GEMM
// Xf: flat [R][512] bf16 (spatial: R=NCH*576 rows are nl*576+l; temporal: rows m*16+t).
// Wb: [1536][512] bf16. 128x128 tile, BK=64, global_load_lds staging (m97 structure).
// mode 0: spatial epilogue (Q/K [l][512] + V [c][576] per nl); mode 1: temporal [m][o][t].
__global__ __launch_bounds__(256) void k_gemm_qkv(const bf16* __restrict__ Xf,
        const bf16* __restrict__ Wb, const void* __restrict__ Bv,
        bf16* __restrict__ Y, const int* __restrict__ flag,
        size_t kOff, size_t vOff, int mode){
  const bool f32in = flag[0] != 0;
  const int nwg = gridDim.x;
  const int bid = blockIdx.x;
  const int g = (bid & 7)*(nwg >> 3) + (bid >> 3);   // chunked XCD swizzle (nwg%8==0)
  const int mt = g / 12, nt = g - mt*12;
  const int r0 = mt*128, o0 = nt*128;
  const int tid = threadIdx.x, lane = tid & 63, w = tid >> 6;
  const int wm = w & 1, wn = w >> 1;
  const int r15 = lane & 15, quad = lane >> 4;
  __shared__ bf16 As[128*64];
  __shared__ bf16 Bs[128*64];
  v4f acc[4][4];
  #pragma unroll
  for (int i = 0; i < 4; ++i)
    #pragma unroll
    for (int j = 0; j < 4; ++j) acc[i][j] = (v4f){0.f,0.f,0.f,0.f};
  for (int kc = 0; kc < 512; kc += 64){
    __syncthreads();
    #pragma unroll
    for (int r = 0; r < 4; ++r){
      int d = (tid + 256*r)*8;         // elem offset in tile; row=d>>6, col=d&63
      int row = d >> 6, col = d & 63;
      async_cp16(&Xf[(size_t)(r0 + row)*512 + kc + col], As + r*2048 + w*512);
      async_cp16(&Wb[(size_t)(o0 + row)*512 + kc + col], Bs + r*2048 + w*512);
    }
    __syncthreads();                    // compiler drains vmcnt(0) before barrier
    #pragma unroll
    for (int ks = 0; ks < 2; ++ks){
      v8s a[4], b[4];
      #pragma unroll
      for (int mi = 0; mi < 4; ++mi)
        a[mi] = *(const v8s*)&As[(wm*64 + mi*16 + r15)*64 + ks*32 + quad*8];
      #pragma unroll
      for (int ni = 0; ni < 4; ++ni)
        b[ni] = *(const v8s*)&Bs[(wn*64 + ni*16 + r15)*64 + ks*32 + quad*8];
      #pragma unroll
      for (int mi = 0; mi < 4; ++mi)
        #pragma unroll
        for (int ni = 0; ni < 4; ++ni)
          acc[mi][ni] = __builtin_amdgcn_mfma_f32_16x16x32_bf16(a[mi], b[ni], acc[mi][ni], 0, 0, 0);
    }
  }
  if (mode == 0){
    #pragma unroll
    for (int ni = 0; ni < 4; ++ni){
      int o = o0 + wn*64 + ni*16 + r15;
      int seg = o >> 9, oseg = o & 511;
      size_t segb = (seg==0) ? 0 : (seg==1) ? kOff : vOff;
      float bia = ldin(Bv, o, f32in);
      #pragma unroll
      for (int mi = 0; mi < 4; ++mi)
        #pragma unroll
        for (int rg = 0; rg < 4; ++rg){
          int rr = r0 + wm*64 + mi*16 + quad*4 + rg;
          int nl = rr / 576, l = rr - nl*576;
          size_t dst = segb + (size_t)nl*294912 +
                       ((seg==2) ? ((size_t)oseg*576 + l) : ((size_t)l*512 + oseg));
          Y[dst] = f2b(acc[mi][ni][rg] + bia);
        }
    }
  } else {
    #pragma unroll
    for (int ni = 0; ni < 4; ++ni){
      int o = o0 + wn*64 + ni*16 + r15;
      float bia = ldin(Bv, o, f32in);
      #pragma unroll
      for (int mi = 0; mi < 4; ++mi)
        #pragma unroll
        for (int rg = 0; rg < 4; ++rg){
          int rr = r0 + wm*64 + mi*16 + quad*4 + rg;
          int m = rr >> 4, t = rr & 15;
          Y[((size_t)m*1536 + o)*16 + t] = f2b(acc[mi][ni][rg] + bia);
        }
    }
  }
}

// ---------------------------------------------------------------- K3: spatial attention (flash MFMA) -> attT [l][c]
__global__ __launch_bounds__(256, 4) void k_attn_s_mfma(const bf16* __restrict__ qkv,
        bf16* __restrict__ attT, size_t kOff, size_t vOff){
  const int bid = blockIdx.x;
  const int xcd = bid & 7, slot = bid >> 3;
  const int nl = xcd + 8*(slot/72);
  const int idx = slot - 72*(slot/72);
  const int head = idx/9, t0 = idx - 9*head;
  const int tid = threadIdx.x, lane = tid & 63, w = tid >> 6;
  const int r15 = lane & 15, quad = lane >> 4;
  __shared__ bf16 Ks[64*72];
  __shared__ bf16 Vs[64*72];
  __shared__ bf16 Ps[4][16*72];
  const bf16* QT = qkv + (size_t)nl*294912;
  const bf16* KT = qkv + kOff + (size_t)nl*294912;
  const bf16* Vp = qkv + vOff + (size_t)nl*294912;
  const int c0 = head*64;
  v8s aq0, aq1;
  {
    const bf16* qrow = QT + (size_t)(t0*64 + w*16 + r15)*512 + c0;
    aq0 = *(const v8s*)(qrow + quad*8);
    aq1 = *(const v8s*)(qrow + 32 + quad*8);
  }
  v4f oc[4];
  #pragma unroll
  for (int ni = 0; ni < 4; ++ni) oc[ni] = (v4f){0.f,0.f,0.f,0.f};
  float m_run[4] = {-1e30f,-1e30f,-1e30f,-1e30f};
  float l_run[4] = {0.f,0.f,0.f,0.f};
  for (int sc = 0; sc < 9; ++sc){
    __syncthreads();
    #pragma unroll
    for (int r = 0; r < 4; ++r){
      int e4 = (tid + 256*r)*4;
      int row = e4 >> 6, col = e4 & 63;
      stage4b(&KT[(size_t)(sc*64 + row)*512 + c0 + col], &Ks[row*72 + col]);
      stage4b(&Vp[(size_t)(c0 + row)*576 + sc*64 + col], &Vs[row*72 + col]);
    }
    __syncthreads();
    v4f sa[4];
    #pragma unroll
    for (int sj = 0; sj < 4; ++sj) sa[sj] = (v4f){0.f,0.f,0.f,0.f};
    #pragma unroll
    for (int sj = 0; sj < 4; ++sj){
      v8s b0 = *(const v8s*)&Ks[(sj*16 + r15)*72 + quad*8];
      v8s b1 = *(const v8s*)&Ks[(sj*16 + r15)*72 + 32 + quad*8];
      sa[sj] = __builtin_amdgcn_mfma_f32_16x16x32_bf16(aq0, b0, sa[sj], 0, 0, 0);
      sa[sj] = __builtin_amdgcn_mfma_f32_16x16x32_bf16(aq1, b1, sa[sj], 0, 0, 0);
    }
    float cmx[4] = {-1e30f,-1e30f,-1e30f,-1e30f};
    #pragma unroll
    for (int sj = 0; sj < 4; ++sj)
      #pragma unroll
      for (int rg = 0; rg < 4; ++rg){
        float v = sa[sj][rg]*0.125f;
        sa[sj][rg] = v;
        cmx[rg] = fmaxf(cmx[rg], v);
      }
    #pragma unroll
    for (int off = 1; off < 16; off <<= 1)
      #pragma unroll
      for (int rg = 0; rg < 4; ++rg) cmx[rg] = fmaxf(cmx[rg], __shfl_xor(cmx[rg], off, 64));
    float alpha[4];
    #pragma unroll
    for (int rg = 0; rg < 4; ++rg){
      float mnew = fmaxf(m_run[rg], cmx[rg]);
      alpha[rg] = __expf(m_run[rg] - mnew);
      m_run[rg] = mnew;
    }
    float psum[4] = {0.f,0.f,0.f,0.f};
    #pragma unroll
    for (int sj = 0; sj < 4; ++sj)
      #pragma unroll
      for (int rg = 0; rg < 4; ++rg){
        float e = __expf(sa[sj][rg] - m_run[rg]);
        sa[sj][rg] = e; psum[rg] += e;
      }
    #pragma unroll
    for (int off = 1; off < 16; off <<= 1)
      #pragma unroll
      for (int rg = 0; rg < 4; ++rg) psum[rg] += __shfl_xor(psum[rg], off, 64);
    #pragma unroll
    for (int rg = 0; rg < 4; ++rg) l_run[rg] = l_run[rg]*alpha[rg] + psum[rg];
    #pragma unroll
    for (int ni = 0; ni < 4; ++ni)
      #pragma unroll
      for (int rg = 0; rg < 4; ++rg) oc[ni][rg] *= alpha[rg];
    #pragma unroll
    for (int sj = 0; sj < 4; ++sj)
      #pragma unroll
      for (int rg = 0; rg < 4; ++rg)
        Ps[w][(quad*4 + rg)*72 + sj*16 + r15] = f2b(sa[sj][rg]);
    #pragma unroll
    for (int ks = 0; ks < 2; ++ks){
      v8s a = *(const v8s*)&Ps[w][r15*72 + ks*32 + quad*8];
      #pragma unroll
      for (int ni = 0; ni < 4; ++ni){
        v8s b = *(const v8s*)&Vs[(ni*16 + r15)*72 + ks*32 + quad*8];
        oc[ni] = __builtin_amdgcn_mfma_f32_16x16x32_bf16(a, b, oc[ni], 0, 0, 0);
      }
    }
  }
  float inv[4];
  #pragma unroll
  for (int rg = 0; rg < 4; ++rg) inv[rg] = 1.f / l_run[rg];
  #pragma unroll
  for (int ni = 0; ni < 4; ++ni)
    #pragma unroll
    for (int rg = 0; rg < 4; ++rg){
      int t = t0*64 + w*16 + quad*4 + rg;
      attT[(size_t)(nl*576 + t)*512 + c0 + ni*16 + r15] = f2b(oc[ni][rg]*inv[rg]);
    }
}

// ---------------------------------------------------------------- K4: spatial proj + residual (MFMA)
// R1: LDS-transpose epilogue with coalesced 16B stores (x2 and x2T).
__global__ __launch_bounds__(256) void k_proj_s_mfma(const bf16* __restrict__ AT,
        const bf16* __restrict__ Wb, const void* __restrict__ Bv,
        const void* __restrict__ xin, bf16* __restrict__ x2,
        bf16* __restrict__ x2T, int doT,
        const int* __restrict__ flag, int n0){
  const bool f32in = flag[0] != 0;
  const int o0 = blockIdx.x * 128;
  const int l0 = blockIdx.y * 64;
  const int nl = blockIdx.z;
  const int n = n0 + nl;
  const int b = n >> 4, t = n & 15;
  const int tid = threadIdx.x, lane = tid & 63;
  const int wm = (tid >> 6) & 1, wn = tid >> 7;
  const int r15 = lane & 15, quad = lane >> 4;
  __shared__ bf16 As[128*72];
  __shared__ bf16 Bs[64*72];
  v4f acc[4][2];
  #pragma unroll
  for (int i = 0; i < 4; ++i)
    #pragma unroll
    for (int j = 0; j < 2; ++j) acc[i][j] = (v4f){0.f,0.f,0.f,0.f};
  for (int kc = 0; kc < 512; kc += 64){
    __syncthreads();
    #pragma unroll
    for (int r = 0; r < 8; ++r){
      int e4 = (tid + 256*r)*4;
      int row = e4 >> 6, k = e4 & 63;
      stage4b(&Wb[(size_t)(o0+row)*512 + kc + k], &As[row*72 + k]);
    }
    #pragma unroll
    for (int r = 0; r < 4; ++r){
      int e4 = (tid + 256*r)*4;
      int row = e4 >> 6, k = e4 & 63;
      stage4b(&AT[(size_t)(nl*576 + l0 + row)*512 + kc + k], &Bs[row*72 + k]);
    }
    __syncthreads();
    #pragma unroll
    for (int ks = 0; ks < 2; ++ks){
      v8s a[4], b[2];
      #pragma unroll
      for (int mi = 0; mi < 4; ++mi)
        a[mi] = *(const v8s*)&As[(wm*64 + mi*16 + r15)*72 + ks*32 + quad*8];
      #pragma unroll
      for (int ni = 0; ni < 2; ++ni)
        b[ni] = *(const v8s*)&Bs[(wn*32 + ni*16 + r15)*72 + ks*32 + quad*8];
      #pragma unroll
      for (int mi = 0; mi < 4; ++mi)
        #pragma unroll
        for (int ni = 0; ni < 2; ++ni)
          acc[mi][ni] = __builtin_amdgcn_mfma_f32_16x16x32_bf16(a[mi], b[ni], acc[mi][ni], 0, 0, 0);
    }
  }
  // -------- epilogue: stage acc+bias into As as [o_rel][l_rel] (stride 72)
  __syncthreads();
  #pragma unroll
  for (int mi = 0; mi < 4; ++mi){
    int orel = wm*64 + mi*16 + quad*4;
    #pragma unroll
    for (int rg = 0; rg < 4; ++rg){
      float bia = ldin(Bv, o0 + orel + rg, f32in);
      #pragma unroll
      for (int ni = 0; ni < 2; ++ni)
        As[(orel + rg)*72 + wn*32 + ni*16 + r15] = f2b(acc[mi][ni][rg] + bia);
    }
  }
  __syncthreads();
  // phase 1: residual add + coalesced x2 write (+writeback for phase 2)
  const size_t xrow = ((size_t)(b*512 + o0)*16 + t)*576 + l0;
  for (int it = 0; it < 4; ++it){
    int idx = tid + it*256;             // 1024 chunks of 8 elems
    int o = idx >> 3, lc = (idx & 7)*8;
    union { bf16 h[8]; v8s v; } val;
    val.v = *(const v8s*)&As[o*72 + lc];
    size_t ga = xrow + (size_t)o*9216 + lc;
    if (f32in){
      const float* xp = (const float*)xin + ga;
      float4 f0 = *(const float4*)xp;
      float4 f1 = *(const float4*)(xp + 4);
      val.h[0] = f2b(b2f(val.h[0]) + f0.x);
      val.h[1] = f2b(b2f(val.h[1]) + f0.y);
      val.h[2] = f2b(b2f(val.h[2]) + f0.z);
      val.h[3] = f2b(b2f(val.h[3]) + f0.w);
      val.h[4] = f2b(b2f(val.h[4]) + f1.x);
      val.h[5] = f2b(b2f(val.h[5]) + f1.y);
      val.h[6] = f2b(b2f(val.h[6]) + f1.z);
      val.h[7] = f2b(b2f(val.h[7]) + f1.w);
    } else {
      union { bf16 h[8]; v8s v; } xv;
      xv.v = *(const v8s*)((const bf16*)xin + ga);
      #pragma unroll
      for (int j = 0; j < 8; ++j) val.h[j] = f2b(b2f(val.h[j]) + b2f(xv.h[j]));
    }
    *(v8s*)&x2[ga] = val.v;
    if (doT) *(v8s*)&As[o*72 + lc] = val.v;
  }
  if (doT){
    __syncthreads();
    // phase 2: x2T [m][t][c]: per chunk, 8 consecutive o at fixed l
    const size_t tbase = ((size_t)b*576 + l0)*8192 + (size_t)t*512 + o0;
    for (int it = 0; it < 4; ++it){
      int l = (tid & 15) + it*16;
      int ocg = (tid >> 4)*8;
      union { bf16 h[8]; v8s v; } val;
      #pragma unroll
      for (int j = 0; j < 8; ++j) val.h[j] = As[(ocg + j)*72 + l];
      *(v8s*)&x2T[tbase + (size_t)l*8192 + ocg] = val.v;
    }
  }
}

// ---------------------------------------------------------------- K5a: temporal groupnorm (scattered x2) -> xnT [m][t][c]
__global__ __launch_bounds__(256) void k_gn_t(const bf16* __restrict__ x2,
        const void* __restrict__ gw, const void* __restrict__ gb,
        bf16* __restrict__ xnT, const int* __restrict__ flag, int m0){
  const bool f32in = flag[0] != 0;
  const int ml = blockIdx.x;
  const int m = m0 + ml;
  const int b = m / 576, l = m - b*576;
  const int tid = threadIdx.x;
  __shared__ float xs[8192];
  __shared__ float mg[32], rg[32];
  for (int i = tid; i < 8192; i += 256){
    int t = i >> 9, c = i & 511;
    xs[i] = b2f(x2[((b*512 + c)*16 + t)*576 + l]);
  }
  __syncthreads();
  {
    int g = tid >> 3, ii = tid & 7;
    float s = 0.f, q = 0.f;
    for (int idx = ii; idx < 256; idx += 8){
      int t = idx >> 4, cg = idx & 15;
      float v = xs[t*512 + g*16 + cg]; s += v; q += v*v;
    }
    #pragma unroll
    for (int off = 1; off < 8; off <<= 1){ s += __shfl_xor(s, off, 64); q += __shfl_xor(q, off, 64); }
    if (ii == 0){
      float mean = s*(1.f/256.f);
      float var  = q*(1.f/256.f) - mean*mean;
      mg[g] = mean; rg[g] = rsqrtf(fmaxf(var, 0.f) + 1e-5f);
    }
  }
  __syncthreads();
  for (int i = tid; i < 8192; i += 256){
    int c = i & 511, g = c >> 4;
    xnT[(size_t)ml*8192 + i] = f2b((xs[i] - mg[g])*rg[g]*ldin(gw, c, f32in) + ldin(gb, c, f32in));
  }
}

// ---------------------------------------------------------------- K5b: temporal groupnorm (coalesced x2T)
__global__ __launch_bounds__(256) void k_gn_t2(const bf16* __restrict__ x2T,
        const void* __restrict__ gw, const void* __restrict__ gb,
        bf16* __restrict__ xnT, const int* __restrict__ flag, int m0){
  const bool f32in = flag[0] != 0;
  const int ml = blockIdx.x;
  const int m = m0 + ml;
  const int tid = threadIdx.x;
  __shared__ float xs[8192];
  __shared__ float mg[32], rg[32];
  for (int i = tid; i < 8192; i += 256)
    xs[i] = b2f(x2T[(size_t)m*8192 + i]);     // [t][c] order, fully coalesced
  __syncthreads();
  {
    int g = tid >> 3, ii = tid & 7;
    float s = 0.f, q = 0.f;
    for (int idx = ii; idx < 256; idx += 8){
      int t = idx >> 4, cg = idx & 15;
      float v = xs[t*512 + g*16 + cg]; s += v; q += v*v;
    }
    #pragma unroll
    for (int off = 1; off < 8; off <<= 1){ s += __shfl_xor(s, off, 64); q += __shfl_xor(q, off, 64); }
    if (ii == 0){
      float mean = s*(1.f/256.f);
      float var  = q*(1.f/256.f) - mean*mean;
      mg[g] = mean; rg[g] = rsqrtf(fmaxf(var, 0.f) + 1e-5f);
    }
  }
  __syncthreads();
  for (int i = tid; i < 8192; i += 256){
    int c = i & 511, g = c >> 4;
    xnT[(size_t)ml*8192 + i] = f2b((xs[i] - mg[g])*rg[g]*ldin(gw, c, f32in) + ldin(gb, c, f32in));
  }
}

// ---------------------------------------------------------------- K7: temporal attention -> attT [m][t][c]
__global__ __launch_bounds__(256) void k_attn_t(const bf16* __restrict__ qkv,
        const void* __restrict__ tbk, const void* __restrict__ tbv,
        bf16* __restrict__ attT, const int* __restrict__ flag){
  const bool f32in = flag[0] != 0;
  const int head = blockIdx.x;
  const int ml = blockIdx.y;
  const int tid = threadIdx.x;
  __shared__ float qsT[16*68], ksT[16*68], vsT[16*68];  // [t][c], stride 68 (16B-aligned rows)
  __shared__ float tks[33*68], tvs[33*68];              // [d][c]
  __shared__ float ps[16*17];
  const int base = (ml*1536 + head*64)*16;
  for (int i = tid; i < 1024; i += 256){
    int c = i >> 4, t = i & 15;
    qsT[t*68 + c] = b2f(qkv[base + i]);
    ksT[t*68 + c] = b2f(qkv[base + 8192 + i]);
    vsT[t*68 + c] = b2f(qkv[base + 16384 + i]);
  }
  for (int i = tid; i < 33*64; i += 256){
    int d = i >> 6, c = i & 63;
    tks[d*68 + c] = ldin(tbk, i, f32in);
    tvs[d*68 + c] = ldin(tbv, i, f32in);
  }
  __syncthreads();
  {
    const int t = tid >> 4, s = tid & 15;
    const float4* qt = (const float4*)&qsT[t*68];
    const float4* kr = (const float4*)&ksT[s*68];
    const float4* q2 = (const float4*)&qsT[s*68];
    const float4* tr = (const float4*)&tks[(t - s + 16)*68];
    float qk = 0.f, rp = 0.f;
    #pragma unroll
    for (int c4 = 0; c4 < 16; ++c4){
      float4 a = qt[c4], b = kr[c4];
      qk += a.x*b.x + a.y*b.y + a.z*b.z + a.w*b.w;
      float4 a2 = q2[c4], tb = tr[c4];
      rp += a2.x*tb.x + a2.y*tb.y + a2.z*tb.z + a2.w*tb.w;
    }
    float logit = 0.125f*qk + 0.35355339059327373f*rp;
    if (s > t) logit = -1e8f;
    float mx = logit;
    #pragma unroll
    for (int off = 8; off; off >>= 1) mx = fmaxf(mx, __shfl_xor(mx, off, 16));
    float e = __expf(logit - mx);
    float tot = e;
    #pragma unroll
    for (int off = 8; off; off >>= 1) tot += __shfl_xor(tot, off, 16);
    ps[t*17 + s] = e / tot;
  }
  __syncthreads();
  {
    const int c4 = tid & 15, t = tid >> 4;
    float4 acc = {0.f,0.f,0.f,0.f};
    #pragma unroll
    for (int s = 0; s < 16; ++s){
      float p = ps[t*17 + s];
      float4 v4 = *(const float4*)&vsT[s*68 + c4*4];
      float4 t4 = *(const float4*)&tvs[(s - t + 16)*68 + c4*4];
      acc.x += p*(v4.x + t4.x); acc.y += p*(v4.y + t4.y);
      acc.z += p*(v4.z + t4.z); acc.w += p*(v4.w + t4.w);
    }
    union { bf16 h[4]; ushort4 u; } o;
    o.h[0] = f2b(acc.x); o.h[1] = f2b(acc.y); o.h[2] = f2b(acc.z); o.h[3] = f2b(acc.w);
    *(ushort4*)&attT[(size_t)ml*8192 + t*512 + head*64 + c4*4] = o.u;
  }
}

// ---------------------------------------------------------------- K8: temporal proj + residual -> out (MFMA, coalesced)
__global__ __launch_bounds__(256) void k_proj_t_mfma(const bf16* __restrict__ AT,
        const bf16* __restrict__ Wb, const void* __restrict__ Bv,
        const bf16* __restrict__ x2, void* __restrict__ out,
        const int* __restrict__ flag, int m0){
  const bool f32in = flag[0] != 0;
  const int o0 = blockIdx.x * 128;
  const int tp = blockIdx.y;            // t-pair
  const int mg0 = blockIdx.z * 32;      // m base (32 | 576)
  const int tid = threadIdx.x, lane = tid & 63;
  const int wm = (tid >> 6) & 1, wn = tid >> 7;
  const int r15 = lane & 15, quad = lane >> 4;
  __shared__ bf16 As[128*72];
  __shared__ bf16 Bs[64*72];
  v4f acc[4][2];
  #pragma unroll
  for (int i = 0; i < 4; ++i)
    #pragma unroll
    for (int j = 0; j < 2; ++j) acc[i][j] = (v4f){0.f,0.f,0.f,0.f};
  for (int kc = 0; kc < 512; kc += 64){
    __syncthreads();
    #pragma unroll
    for (int r = 0; r < 8; ++r){
      int e4 = (tid + 256*r)*4;
      int row = e4 >> 6, k = e4 & 63;
      stage4b(&Wb[(size_t)(o0+row)*512 + kc + k], &As[row*72 + k]);
    }
    #pragma unroll
    for (int r = 0; r < 4; ++r){
      int e4 = (tid + 256*r)*4;
      int row = e4 >> 6, k = e4 & 63;
      stage4b(&AT[(size_t)(mg0 + (row & 31))*8192 + (tp*2 + (row >> 5))*512 + kc + k],
              &Bs[row*72 + k]);
    }
    __syncthreads();
    #pragma unroll
    for (int ks = 0; ks < 2; ++ks){
      v8s a[4], b[2];
      #pragma unroll
      for (int mi = 0; mi < 4; ++mi)
        a[mi] = *(const v8s*)&As[(wm*64 + mi*16 + r15)*72 + ks*32 + quad*8];
      #pragma unroll
      for (int ni = 0; ni < 2; ++ni)
        b[ni] = *(const v8s*)&Bs[(wn*32 + ni*16 + r15)*72 + ks*32 + quad*8];
      #pragma unroll
      for (int mi = 0; mi < 4; ++mi)
        #pragma unroll
        for (int ni = 0; ni < 2; ++ni)
          acc[mi][ni] = __builtin_amdgcn_mfma_f32_16x16x32_bf16(a[mi], b[ni], acc[mi][ni], 0, 0, 0);
    }
  }
  const int tt = tp*2 + wn;
  #pragma unroll
  for (int mi = 0; mi < 4; ++mi)
    #pragma unroll
    for (int rg = 0; rg < 4; ++rg){
      int o = o0 + wm*64 + mi*16 + quad*4 + rg;
      float bia = ldin(Bv, o, f32in);
      #pragma unroll
      for (int ni = 0; ni < 2; ++ni){
        int m = m0 + mg0 + ni*16 + r15;
        int b = m / 576, l = m - b*576;
        size_t addr = ((size_t)(b*512 + o)*16 + tt)*576 + l;
        float val = acc[mi][ni][rg] + bia + b2f(x2[addr]);
        if (f32in) ((float*)out)[addr] = val;
        else       ((bf16*)out)[addr] = f2b(val);
      }
    }
}

// ----------------------------------------------------------------
extern "C" void kernel_launch(void* const* d_in, const int* in_sizes, int n_in,
                              void* d_out, int out_size, void* d_ws, size_t ws_size,
                              hipStream_t stream){
  const void* x   = d_in[0];
  const void* nsw = d_in[1];
  const void* nsb = d_in[2];
  const void* qsw = d_in[3];
  const void* qsb = d_in[4];
  const void* psw = d_in[5];
  const void* psb = d_in[6];
  const void* ntw = d_in[7];
  const void* ntb = d_in[8];
  const void* qtw = d_in[9];
  const void* qtb = d_in[10];
  const void* ptw = d_in[11];
  const void* ptb = d_in[12];
  const void* rpk = d_in[13];
  const void* rpv = d_in[14];

  // Chunking and x2T gate from ws_size (constant across calls -> graph-safe).
  const size_t S_full = (size_t)32*294912;
  const size_t need_full = 256 + (S_full*5 + 9437184)*2;
  const size_t need_T    = 256 + (S_full*5 + (size_t)2*9437184)*2;  // +18.9 MB for x2T
  const int NCH = (ws_size >= need_full) ? 32 : 8;
  const int MCH = (NCH == 32) ? 1152 : 288;
  const size_t S = (size_t)NCH*294912;
  const int useT = (NCH == 32 && ws_size >= need_T) ? 1 : 0;

  int*  flag = (int*)d_ws;
  bf16* A  = (bf16*)((char*)d_ws + 256);   // S: xnT_s / xnT_t
  bf16* A2 = A  + S;                        // S: attT_s / attT_t (+ transient W copy)
  bf16* Bq = A2 + S;                        // 3S: qkv (+ transient W copies)
  bf16* Cx = Bq + 3*S;                      // 9,437,184: x2 residual
  bf16* Cx2 = Cx + 9437184;                 // 9,437,184: x2T [m][t][c] (if useT)
  const size_t kOff = S, vOff = 2*S;
  bf16* Wcv  = A2;
  bf16* Wcv2 = Bq;

  k_detect<<<1, 64, 0, stream>>>(x, flag);

  for (int n0 = 0; n0 < 32; n0 += NCH){
    k_gn_s       <<<dim3(32, NCH),   256, 0, stream>>>(x, nsw, nsb, A, flag, n0);
    k_cvtw       <<<dim3(768),       256, 0, stream>>>(qsw, Wcv, 196608, flag);
    k_gemm_qkv   <<<dim3(NCH*54),    256, 0, stream>>>(A, Wcv, qsb, Bq, flag, kOff, vOff, 0);
    k_attn_s_mfma<<<dim3(72*NCH),    256, 0, stream>>>(Bq, A2, kOff, vOff);
    // proj_s weight pre-convert into Bq (qkv dead after attn_s)
    k_cvtw       <<<dim3(256),       256, 0, stream>>>(psw, Bq, 65536, flag);
    k_proj_s_mfma<<<dim3(4, 9, NCH), 256, 0, stream>>>(A2, Bq, psb, x, Cx, Cx2, useT, flag, n0);
  }
  for (int m0 = 0; m0 < 1152; m0 += MCH){
    if (useT) k_gn_t2<<<dim3(MCH),   256, 0, stream>>>(Cx2, ntw, ntb, A, flag, m0);
    else      k_gn_t <<<dim3(MCH),   256, 0, stream>>>(Cx,  ntw, ntb, A, flag, m0);
    k_cvtw       <<<dim3(768),       256, 0, stream>>>(qtw, Wcv, 196608, flag);
    k_gemm_qkv   <<<dim3((MCH/2)*3), 256, 0, stream>>>(A, Wcv, qtb, Bq, flag, 0, 0, 1);
    k_attn_t     <<<dim3(8, MCH),    256, 0, stream>>>(Bq, rpk, rpv, A2, flag);
    k_cvtw       <<<dim3(256),       256, 0, stream>>>(ptw, Wcv2, 65536, flag);
    k_proj_t_mfma<<<dim3(4, 8, MCH/32), 256, 0, stream>>>(A2, Wcv2, ptb, Cx, d_out, flag, m0);
  }
}

// Round 4
// 507.115 us; speedup vs baseline: 1.1723x; 1.0072x over previous
//
#include <hip/hip_runtime.h>
#include <hip/hip_bf16.h>

typedef __hip_bfloat16 bf16;
typedef __attribute__((ext_vector_type(8))) short v8s;
typedef __attribute__((ext_vector_type(4))) float v4f;

__device__ __forceinline__ float b2f(bf16 v){ return __bfloat162float(v); }
__device__ __forceinline__ bf16  f2b(float v){ return __float2bfloat16(v); }

// Inputs may be bf16 OR f32 — runtime-detected flag (1 => f32). Output dtype follows.
__device__ __forceinline__ float ldin(const void* p, int i, bool f32in){
  return f32in ? ((const float*)p)[i] : b2f(((const bf16*)p)[i]);
}

// stage 4 consecutive source elems (f32-or-bf16) into dst as bf16 (8B write)
__device__ __forceinline__ void stage4(const void* src, size_t off, bool f32in, bf16* dst){
  union { bf16 h[4]; ushort4 u; } tmp;
  if (f32in){
    float4 f = *(const float4*)((const float*)src + off);
    tmp.h[0] = f2b(f.x); tmp.h[1] = f2b(f.y); tmp.h[2] = f2b(f.z); tmp.h[3] = f2b(f.w);
  } else {
    tmp.u = *(const ushort4*)((const ushort*)src + off);
  }
  *(ushort4*)dst = tmp.u;
}
__device__ __forceinline__ void stage4b(const bf16* src, bf16* dst){
  *(ushort4*)dst = *(const ushort4*)src;
}

// async global->LDS, 16B per lane. LDS dest must be wave-uniform base (HW adds lane*16).
__device__ __forceinline__ void async_cp16(const bf16* g, bf16* l){
  __builtin_amdgcn_global_load_lds(
      (const __attribute__((address_space(1))) unsigned int*)g,
      (__attribute__((address_space(3))) unsigned int*)l, 16, 0, 0);
}

// Problem: B=2, C=512, T=16, H=W=24, heads=8, ch=64
// ws: flag | A (S) | A2 (S) | Bq (3S) | Cx 9,437,184 | [Cx2 9,437,184 if room]
// R1: proj_s epilogue was request-bound -> LDS-transpose epilogue (WIN, -58us).
// R2: qkv GEMMs latency-bound -> unified 128x128 global_load_lds GEMM (+tile win,
//     but linear 128B LDS rows caused 16-way bank conflict: 1.06e7, dur 85us).
// R3: XOR-swizzle slot^=(row&7): inverse-swizzled GLOBAL source (gload_lds dest
//     must stay linear) + swizzled ds_read (rule #21 both-sides-or-neither).

// ---------------------------------------------------------------- detect input dtype
__global__ void k_detect(const void* x, int* flag){
  int tid = threadIdx.x;
  const bf16* p = (const bf16*)x;
  int cnt = 0;
  for (int i = tid; i < 512; i += 64){
    float v = b2f(p[i]);
    if (!(fabsf(v) <= 64.f)) cnt++;
  }
  #pragma unroll
  for (int off = 32; off; off >>= 1) cnt += __shfl_down(cnt, off, 64);
  if (tid == 0) flag[0] = (cnt > 16) ? 1 : 0;
}

// ---------------------------------------------------------------- weight convert -> bf16 scratch
__global__ __launch_bounds__(256) void k_cvtw(const void* __restrict__ W,
        bf16* __restrict__ out, int n4, const int* __restrict__ flag){
  const bool f32in = flag[0] != 0;
  int i = blockIdx.x*256 + threadIdx.x;
  if (i < n4) stage4(W, (size_t)i*4, f32in, out + (size_t)i*4);
}

// ---------------------------------------------------------------- K1: spatial groupnorm -> xnT [l][c]
__global__ __launch_bounds__(256) void k_gn_s(const void* __restrict__ x,
        const void* __restrict__ gw, const void* __restrict__ gb,
        bf16* __restrict__ xnT, const int* __restrict__ flag, int n0){
  const bool f32in = flag[0] != 0;
  const int g = blockIdx.x;
  const int nl = blockIdx.y;
  const int n = n0 + nl;
  const int b = n >> 4, t = n & 15;
  const int tid = threadIdx.x;
  __shared__ float xs[576*17];     // [l][cg] padded
  __shared__ float red[4][2];
  __shared__ float stats[2];
  float s = 0.f, q = 0.f;
  for (int i = tid; i < 9216; i += 256){
    int cg = i / 576, l = i - cg*576;
    int c = g*16 + cg;
    float v = ldin(x, ((b*512 + c)*16 + t)*576 + l, f32in);
    xs[l*17 + cg] = v; s += v; q += v*v;
  }
  #pragma unroll
  for (int off = 32; off; off >>= 1){ s += __shfl_down(s, off, 64); q += __shfl_down(q, off, 64); }
  int wid = tid >> 6;
  if ((tid & 63) == 0){ red[wid][0] = s; red[wid][1] = q; }
  __syncthreads();
  if (tid == 0){
    float S = red[0][0]+red[1][0]+red[2][0]+red[3][0];
    float Q = red[0][1]+red[1][1]+red[2][1]+red[3][1];
    float mean = S * (1.f/9216.f);
    float var  = Q * (1.f/9216.f) - mean*mean;
    stats[0] = mean; stats[1] = rsqrtf(fmaxf(var, 0.f) + 1e-5f);
  }
  __syncthreads();
  float mean = stats[0], rstd = stats[1];
  for (int i = tid; i < 9216; i += 256){
    int l = i >> 4, cg = i & 15;
    int c = g*16 + cg;
    xnT[(size_t)(nl*576 + l)*512 + c] =
        f2b((xs[l*17 + cg] - mean)*rstd*ldin(gw, c, f32in) + ldin(gb, c, f32in));
  }
}

// ---------------------------------------------------------------- K2/K6: unified qkv GEMM
// Xf: flat [R][512] bf16. Wb: [1536][512] bf16. 128x128 tile, BK=64,
// global_load_lds staging into linear LDS; slot^=(row&7) XOR swizzle applied
// via pre-swizzled global source + swizzled ds_read (T2 / rule #21).
// mode 0: spatial epilogue (Q/K [l][512] + V [c][576] per nl); mode 1: temporal [m][o][t].
__global__ __launch_bounds__(256) void k_gemm_qkv(const bf16* __restrict__ Xf,
        const bf16* __restrict__ Wb, const void* __restrict__ Bv,
        bf16* __restrict__ Y, const int* __restrict__ flag,
        size_t kOff, size_t vOff, int mode){
  const bool f32in = flag[0] != 0;
  const int nwg = gridDim.x;
  const int bid = blockIdx.x;
  const int g = (bid & 7)*(nwg >> 3) + (bid >> 3);   // chunked XCD swizzle (nwg%8==0)
  const int mt = g / 12, nt = g - mt*12;
  const int r0 = mt*128, o0 = nt*128;
  const int tid = threadIdx.x, lane = tid & 63, w = tid >> 6;
  const int wm = w & 1, wn = w >> 1;
  const int r15 = lane & 15, quad = lane >> 4;
  const int rsw = r15 & 7;                 // read-side swizzle key (row&7 == r15&7)
  __shared__ bf16 As[128*64];
  __shared__ bf16 Bs[128*64];
  v4f acc[4][4];
  #pragma unroll
  for (int i = 0; i < 4; ++i)
    #pragma unroll
    for (int j = 0; j < 4; ++j) acc[i][j] = (v4f){0.f,0.f,0.f,0.f};
  for (int kc = 0; kc < 512; kc += 64){
    __syncthreads();
    #pragma unroll
    for (int r = 0; r < 4; ++r){
      int d = (tid + 256*r)*8;             // linear LDS elem offset this lane fills
      int row = d >> 6;
      int slot = (d >> 3) & 7;             // 16B slot within the 128B row
      int col = ((slot ^ (row & 7)) * 8);  // inverse-swizzled source column
      async_cp16(&Xf[(size_t)(r0 + row)*512 + kc + col], As + r*2048 + w*512);
      async_cp16(&Wb[(size_t)(o0 + row)*512 + kc + col], Bs + r*2048 + w*512);
    }
    __syncthreads();                        // compiler drains vmcnt(0) before barrier
    #pragma unroll
    for (int ks = 0; ks < 2; ++ks){
      v8s a[4], b[4];
      #pragma unroll
      for (int mi = 0; mi < 4; ++mi)
        a[mi] = *(const v8s*)&As[(wm*64 + mi*16 + r15)*64 + (((ks*4 + quad) ^ rsw)*8)];
      #pragma unroll
      for (int ni = 0; ni < 4; ++ni)
        b[ni] = *(const v8s*)&Bs[(wn*64 + ni*16 + r15)*64 + (((ks*4 + quad) ^ rsw)*8)];
      #pragma unroll
      for (int mi = 0; mi < 4; ++mi)
        #pragma unroll
        for (int ni = 0; ni < 4; ++ni)
          acc[mi][ni] = __builtin_amdgcn_mfma_f32_16x16x32_bf16(a[mi], b[ni], acc[mi][ni], 0, 0, 0);
    }
  }
  if (mode == 0){
    #pragma unroll
    for (int ni = 0; ni < 4; ++ni){
      int o = o0 + wn*64 + ni*16 + r15;
      int seg = o >> 9, oseg = o & 511;
      size_t segb = (seg==0) ? 0 : (seg==1) ? kOff : vOff;
      float bia = ldin(Bv, o, f32in);
      #pragma unroll
      for (int mi = 0; mi < 4; ++mi)
        #pragma unroll
        for (int rg = 0; rg < 4; ++rg){
          int rr = r0 + wm*64 + mi*16 + quad*4 + rg;
          int nl = rr / 576, l = rr - nl*576;
          size_t dst = segb + (size_t)nl*294912 +
                       ((seg==2) ? ((size_t)oseg*576 + l) : ((size_t)l*512 + oseg));
          Y[dst] = f2b(acc[mi][ni][rg] + bia);
        }
    }
  } else {
    #pragma unroll
    for (int ni = 0; ni < 4; ++ni){
      int o = o0 + wn*64 + ni*16 + r15;
      float bia = ldin(Bv, o, f32in);
      #pragma unroll
      for (int mi = 0; mi < 4; ++mi)
        #pragma unroll
        for (int rg = 0; rg < 4; ++rg){
          int rr = r0 + wm*64 + mi*16 + quad*4 + rg;
          int m = rr >> 4, t = rr & 15;
          Y[((size_t)m*1536 + o)*16 + t] = f2b(acc[mi][ni][rg] + bia);
        }
    }
  }
}

// ---------------------------------------------------------------- K3: spatial attention (flash MFMA) -> attT [l][c]
__global__ __launch_bounds__(256, 4) void k_attn_s_mfma(const bf16* __restrict__ qkv,
        bf16* __restrict__ attT, size_t kOff, size_t vOff){
  const int bid = blockIdx.x;
  const int xcd = bid & 7, slot = bid >> 3;
  const int nl = xcd + 8*(slot/72);
  const int idx = slot - 72*(slot/72);
  const int head = idx/9, t0 = idx - 9*head;
  const int tid = threadIdx.x, lane = tid & 63, w = tid >> 6;
  const int r15 = lane & 15, quad = lane >> 4;
  __shared__ bf16 Ks[64*72];
  __shared__ bf16 Vs[64*72];
  __shared__ bf16 Ps[4][16*72];
  const bf16* QT = qkv + (size_t)nl*294912;
  const bf16* KT = qkv + kOff + (size_t)nl*294912;
  const bf16* Vp = qkv + vOff + (size_t)nl*294912;
  const int c0 = head*64;
  v8s aq0, aq1;
  {
    const bf16* qrow = QT + (size_t)(t0*64 + w*16 + r15)*512 + c0;
    aq0 = *(const v8s*)(qrow + quad*8);
    aq1 = *(const v8s*)(qrow + 32 + quad*8);
  }
  v4f oc[4];
  #pragma unroll
  for (int ni = 0; ni < 4; ++ni) oc[ni] = (v4f){0.f,0.f,0.f,0.f};
  float m_run[4] = {-1e30f,-1e30f,-1e30f,-1e30f};
  float l_run[4] = {0.f,0.f,0.f,0.f};
  for (int sc = 0; sc < 9; ++sc){
    __syncthreads();
    #pragma unroll
    for (int r = 0; r < 4; ++r){
      int e4 = (tid + 256*r)*4;
      int row = e4 >> 6, col = e4 & 63;
      stage4b(&KT[(size_t)(sc*64 + row)*512 + c0 + col], &Ks[row*72 + col]);
      stage4b(&Vp[(size_t)(c0 + row)*576 + sc*64 + col], &Vs[row*72 + col]);
    }
    __syncthreads();
    v4f sa[4];
    #pragma unroll
    for (int sj = 0; sj < 4; ++sj) sa[sj] = (v4f){0.f,0.f,0.f,0.f};
    #pragma unroll
    for (int sj = 0; sj < 4; ++sj){
      v8s b0 = *(const v8s*)&Ks[(sj*16 + r15)*72 + quad*8];
      v8s b1 = *(const v8s*)&Ks[(sj*16 + r15)*72 + 32 + quad*8];
      sa[sj] = __builtin_amdgcn_mfma_f32_16x16x32_bf16(aq0, b0, sa[sj], 0, 0, 0);
      sa[sj] = __builtin_amdgcn_mfma_f32_16x16x32_bf16(aq1, b1, sa[sj], 0, 0, 0);
    }
    float cmx[4] = {-1e30f,-1e30f,-1e30f,-1e30f};
    #pragma unroll
    for (int sj = 0; sj < 4; ++sj)
      #pragma unroll
      for (int rg = 0; rg < 4; ++rg){
        float v = sa[sj][rg]*0.125f;
        sa[sj][rg] = v;
        cmx[rg] = fmaxf(cmx[rg], v);
      }
    #pragma unroll
    for (int off = 1; off < 16; off <<= 1)
      #pragma unroll
      for (int rg = 0; rg < 4; ++rg) cmx[rg] = fmaxf(cmx[rg], __shfl_xor(cmx[rg], off, 64));
    float alpha[4];
    #pragma unroll
    for (int rg = 0; rg < 4; ++rg){
      float mnew = fmaxf(m_run[rg], cmx[rg]);
      alpha[rg] = __expf(m_run[rg] - mnew);
      m_run[rg] = mnew;
    }
    float psum[4] = {0.f,0.f,0.f,0.f};
    #pragma unroll
    for (int sj = 0; sj < 4; ++sj)
      #pragma unroll
      for (int rg = 0; rg < 4; ++rg){
        float e = __expf(sa[sj][rg] - m_run[rg]);
        sa[sj][rg] = e; psum[rg] += e;
      }
    #pragma unroll
    for (int off = 1; off < 16; off <<= 1)
      #pragma unroll
      for (int rg = 0; rg < 4; ++rg) psum[rg] += __shfl_xor(psum[rg], off, 64);
    #pragma unroll
    for (int rg = 0; rg < 4; ++rg) l_run[rg] = l_run[rg]*alpha[rg] + psum[rg];
    #pragma unroll
    for (int ni = 0; ni < 4; ++ni)
      #pragma unroll
      for (int rg = 0; rg < 4; ++rg) oc[ni][rg] *= alpha[rg];
    #pragma unroll
    for (int sj = 0; sj < 4; ++sj)
      #pragma unroll
      for (int rg = 0; rg < 4; ++rg)
        Ps[w][(quad*4 + rg)*72 + sj*16 + r15] = f2b(sa[sj][rg]);
    #pragma unroll
    for (int ks = 0; ks < 2; ++ks){
      v8s a = *(const v8s*)&Ps[w][r15*72 + ks*32 + quad*8];
      #pragma unroll
      for (int ni = 0; ni < 4; ++ni){
        v8s b = *(const v8s*)&Vs[(ni*16 + r15)*72 + ks*32 + quad*8];
        oc[ni] = __builtin_amdgcn_mfma_f32_16x16x32_bf16(a, b, oc[ni], 0, 0, 0);
      }
    }
  }
  float inv[4];
  #pragma unroll
  for (int rg = 0; rg < 4; ++rg) inv[rg] = 1.f / l_run[rg];
  #pragma unroll
  for (int ni = 0; ni < 4; ++ni)
    #pragma unroll
    for (int rg = 0; rg < 4; ++rg){
      int t = t0*64 + w*16 + quad*4 + rg;
      attT[(size_t)(nl*576 + t)*512 + c0 + ni*16 + r15] = f2b(oc[ni][rg]*inv[rg]);
    }
}

// ---------------------------------------------------------------- K4: spatial proj + residual (MFMA)
// R1: LDS-transpose epilogue with coalesced 16B stores (x2 and x2T).
__global__ __launch_bounds__(256) void k_proj_s_mfma(const bf16* __restrict__ AT,
        const bf16* __restrict__ Wb, const void* __restrict__ Bv,
        const void* __restrict__ xin, bf16* __restrict__ x2,
        bf16* __restrict__ x2T, int doT,
        const int* __restrict__ flag, int n0){
  const bool f32in = flag[0] != 0;
  const int o0 = blockIdx.x * 128;
  const int l0 = blockIdx.y * 64;
  const int nl = blockIdx.z;
  const int n = n0 + nl;
  const int b = n >> 4, t = n & 15;
  const int tid = threadIdx.x, lane = tid & 63;
  const int wm = (tid >> 6) & 1, wn = tid >> 7;
  const int r15 = lane & 15, quad = lane >> 4;
  __shared__ bf16 As[128*72];
  __shared__ bf16 Bs[64*72];
  v4f acc[4][2];
  #pragma unroll
  for (int i = 0; i < 4; ++i)
    #pragma unroll
    for (int j = 0; j < 2; ++j) acc[i][j] = (v4f){0.f,0.f,0.f,0.f};
  for (int kc = 0; kc < 512; kc += 64){
    __syncthreads();
    #pragma unroll
    for (int r = 0; r < 8; ++r){
      int e4 = (tid + 256*r)*4;
      int row = e4 >> 6, k = e4 & 63;
      stage4b(&Wb[(size_t)(o0+row)*512 + kc + k], &As[row*72 + k]);
    }
    #pragma unroll
    for (int r = 0; r < 4; ++r){
      int e4 = (tid + 256*r)*4;
      int row = e4 >> 6, k = e4 & 63;
      stage4b(&AT[(size_t)(nl*576 + l0 + row)*512 + kc + k], &Bs[row*72 + k]);
    }
    __syncthreads();
    #pragma unroll
    for (int ks = 0; ks < 2; ++ks){
      v8s a[4], b[2];
      #pragma unroll
      for (int mi = 0; mi < 4; ++mi)
        a[mi] = *(const v8s*)&As[(wm*64 + mi*16 + r15)*72 + ks*32 + quad*8];
      #pragma unroll
      for (int ni = 0; ni < 2; ++ni)
        b[ni] = *(const v8s*)&Bs[(wn*32 + ni*16 + r15)*72 + ks*32 + quad*8];
      #pragma unroll
      for (int mi = 0; mi < 4; ++mi)
        #pragma unroll
        for (int ni = 0; ni < 2; ++ni)
          acc[mi][ni] = __builtin_amdgcn_mfma_f32_16x16x32_bf16(a[mi], b[ni], acc[mi][ni], 0, 0, 0);
    }
  }
  // -------- epilogue: stage acc+bias into As as [o_rel][l_rel] (stride 72)
  __syncthreads();
  #pragma unroll
  for (int mi = 0; mi < 4; ++mi){
    int orel = wm*64 + mi*16 + quad*4;
    #pragma unroll
    for (int rg = 0; rg < 4; ++rg){
      float bia = ldin(Bv, o0 + orel + rg, f32in);
      #pragma unroll
      for (int ni = 0; ni < 2; ++ni)
        As[(orel + rg)*72 + wn*32 + ni*16 + r15] = f2b(acc[mi][ni][rg] + bia);
    }
  }
  __syncthreads();
  // phase 1: residual add + coalesced x2 write (+writeback for phase 2)
  const size_t xrow = ((size_t)(b*512 + o0)*16 + t)*576 + l0;
  for (int it = 0; it < 4; ++it){
    int idx = tid + it*256;             // 1024 chunks of 8 elems
    int o = idx >> 3, lc = (idx & 7)*8;
    union { bf16 h[8]; v8s v; } val;
    val.v = *(const v8s*)&As[o*72 + lc];
    size_t ga = xrow + (size_t)o*9216 + lc;
    if (f32in){
      const float* xp = (const float*)xin + ga;
      float4 f0 = *(const float4*)xp;
      float4 f1 = *(const float4*)(xp + 4);
      val.h[0] = f2b(b2f(val.h[0]) + f0.x);
      val.h[1] = f2b(b2f(val.h[1]) + f0.y);
      val.h[2] = f2b(b2f(val.h[2]) + f0.z);
      val.h[3] = f2b(b2f(val.h[3]) + f0.w);
      val.h[4] = f2b(b2f(val.h[4]) + f1.x);
      val.h[5] = f2b(b2f(val.h[5]) + f1.y);
      val.h[6] = f2b(b2f(val.h[6]) + f1.z);
      val.h[7] = f2b(b2f(val.h[7]) + f1.w);
    } else {
      union { bf16 h[8]; v8s v; } xv;
      xv.v = *(const v8s*)((const bf16*)xin + ga);
      #pragma unroll
      for (int j = 0; j < 8; ++j) val.h[j] = f2b(b2f(val.h[j]) + b2f(xv.h[j]));
    }
    *(v8s*)&x2[ga] = val.v;
    if (doT) *(v8s*)&As[o*72 + lc] = val.v;
  }
  if (doT){
    __syncthreads();
    // phase 2: x2T [m][t][c]: per chunk, 8 consecutive o at fixed l
    const size_t tbase = ((size_t)b*576 + l0)*8192 + (size_t)t*512 + o0;
    for (int it = 0; it < 4; ++it){
      int l = (tid & 15) + it*16;
      int ocg = (tid >> 4)*8;
      union { bf16 h[8]; v8s v; } val;
      #pragma unroll
      for (int j = 0; j < 8; ++j) val.h[j] = As[(ocg + j)*72 + l];
      *(v8s*)&x2T[tbase + (size_t)l*8192 + ocg] = val.v;
    }
  }
}

// ---------------------------------------------------------------- K5a: temporal groupnorm (scattered x2) -> xnT [m][t][c]
__global__ __launch_bounds__(256) void k_gn_t(const bf16* __restrict__ x2,
        const void* __restrict__ gw, const void* __restrict__ gb,
        bf16* __restrict__ xnT, const int* __restrict__ flag, int m0){
  const bool f32in = flag[0] != 0;
  const int ml = blockIdx.x;
  const int m = m0 + ml;
  const int b = m / 576, l = m - b*576;
  const int tid = threadIdx.x;
  __shared__ float xs[8192];
  __shared__ float mg[32], rg[32];
  for (int i = tid; i < 8192; i += 256){
    int t = i >> 9, c = i & 511;
    xs[i] = b2f(x2[((b*512 + c)*16 + t)*576 + l]);
  }
  __syncthreads();
  {
    int g = tid >> 3, ii = tid & 7;
    float s = 0.f, q = 0.f;
    for (int idx = ii; idx < 256; idx += 8){
      int t = idx >> 4, cg = idx & 15;
      float v = xs[t*512 + g*16 + cg]; s += v; q += v*v;
    }
    #pragma unroll
    for (int off = 1; off < 8; off <<= 1){ s += __shfl_xor(s, off, 64); q += __shfl_xor(q, off, 64); }
    if (ii == 0){
      float mean = s*(1.f/256.f);
      float var  = q*(1.f/256.f) - mean*mean;
      mg[g] = mean; rg[g] = rsqrtf(fmaxf(var, 0.f) + 1e-5f);
    }
  }
  __syncthreads();
  for (int i = tid; i < 8192; i += 256){
    int c = i & 511, g = c >> 4;
    xnT[(size_t)ml*8192 + i] = f2b((xs[i] - mg[g])*rg[g]*ldin(gw, c, f32in) + ldin(gb, c, f32in));
  }
}

// ---------------------------------------------------------------- K5b: temporal groupnorm (coalesced x2T)
__global__ __launch_bounds__(256) void k_gn_t2(const bf16* __restrict__ x2T,
        const void* __restrict__ gw, const void* __restrict__ gb,
        bf16* __restrict__ xnT, const int* __restrict__ flag, int m0){
  const bool f32in = flag[0] != 0;
  const int ml = blockIdx.x;
  const int m = m0 + ml;
  const int tid = threadIdx.x;
  __shared__ float xs[8192];
  __shared__ float mg[32], rg[32];
  for (int i = tid; i < 8192; i += 256)
    xs[i] = b2f(x2T[(size_t)m*8192 + i]);     // [t][c] order, fully coalesced
  __syncthreads();
  {
    int g = tid >> 3, ii = tid & 7;
    float s = 0.f, q = 0.f;
    for (int idx = ii; idx < 256; idx += 8){
      int t = idx >> 4, cg = idx & 15;
      float v = xs[t*512 + g*16 + cg]; s += v; q += v*v;
    }
    #pragma unroll
    for (int off = 1; off < 8; off <<= 1){ s += __shfl_xor(s, off, 64); q += __shfl_xor(q, off, 64); }
    if (ii == 0){
      float mean = s*(1.f/256.f);
      float var  = q*(1.f/256.f) - mean*mean;
      mg[g] = mean; rg[g] = rsqrtf(fmaxf(var, 0.f) + 1e-5f);
    }
  }
  __syncthreads();
  for (int i = tid; i < 8192; i += 256){
    int c = i & 511, g = c >> 4;
    xnT[(size_t)ml*8192 + i] = f2b((xs[i] - mg[g])*rg[g]*ldin(gw, c, f32in) + ldin(gb, c, f32in));
  }
}

// ---------------------------------------------------------------- K7: temporal attention -> attT [m][t][c]
__global__ __launch_bounds__(256) void k_attn_t(const bf16* __restrict__ qkv,
        const void* __restrict__ tbk, const void* __restrict__ tbv,
        bf16* __restrict__ attT, const int* __restrict__ flag){
  const bool f32in = flag[0] != 0;
  const int head = blockIdx.x;
  const int ml = blockIdx.y;
  const int tid = threadIdx.x;
  __shared__ float qsT[16*68], ksT[16*68], vsT[16*68];  // [t][c], stride 68 (16B-aligned rows)
  __shared__ float tks[33*68], tvs[33*68];              // [d][c]
  __shared__ float ps[16*17];
  const int base = (ml*1536 + head*64)*16;
  for (int i = tid; i < 1024; i += 256){
    int c = i >> 4, t = i & 15;
    qsT[t*68 + c] = b2f(qkv[base + i]);
    ksT[t*68 + c] = b2f(qkv[base + 8192 + i]);
    vsT[t*68 + c] = b2f(qkv[base + 16384 + i]);
  }
  for (int i = tid; i < 33*64; i += 256){
    int d = i >> 6, c = i & 63;
    tks[d*68 + c] = ldin(tbk, i, f32in);
    tvs[d*68 + c] = ldin(tbv, i, f32in);
  }
  __syncthreads();
  {
    const int t = tid >> 4, s = tid & 15;
    const float4* qt = (const float4*)&qsT[t*68];
    const float4* kr = (const float4*)&ksT[s*68];
    const float4* q2 = (const float4*)&qsT[s*68];
    const float4* tr = (const float4*)&tks[(t - s + 16)*68];
    float qk = 0.f, rp = 0.f;
    #pragma unroll
    for (int c4 = 0; c4 < 16; ++c4){
      float4 a = qt[c4], b = kr[c4];
      qk += a.x*b.x + a.y*b.y + a.z*b.z + a.w*b.w;
      float4 a2 = q2[c4], tb = tr[c4];
      rp += a2.x*tb.x + a2.y*tb.y + a2.z*tb.z + a2.w*tb.w;
    }
    float logit = 0.125f*qk + 0.35355339059327373f*rp;
    if (s > t) logit = -1e8f;
    float mx = logit;
    #pragma unroll
    for (int off = 8; off; off >>= 1) mx = fmaxf(mx, __shfl_xor(mx, off, 16));
    float e = __expf(logit - mx);
    float tot = e;
    #pragma unroll
    for (int off = 8; off; off >>= 1) tot += __shfl_xor(tot, off, 16);
    ps[t*17 + s] = e / tot;
  }
  __syncthreads();
  {
    const int c4 = tid & 15, t = tid >> 4;
    float4 acc = {0.f,0.f,0.f,0.f};
    #pragma unroll
    for (int s = 0; s < 16; ++s){
      float p = ps[t*17 + s];
      float4 v4 = *(const float4*)&vsT[s*68 + c4*4];
      float4 t4 = *(const float4*)&tvs[(s - t + 16)*68 + c4*4];
      acc.x += p*(v4.x + t4.x); acc.y += p*(v4.y + t4.y);
      acc.z += p*(v4.z + t4.z); acc.w += p*(v4.w + t4.w);
    }
    union { bf16 h[4]; ushort4 u; } o;
    o.h[0] = f2b(acc.x); o.h[1] = f2b(acc.y); o.h[2] = f2b(acc.z); o.h[3] = f2b(acc.w);
    *(ushort4*)&attT[(size_t)ml*8192 + t*512 + head*64 + c4*4] = o.u;
  }
}

// ---------------------------------------------------------------- K8: temporal proj + residual -> out (MFMA, coalesced)
__global__ __launch_bounds__(256) void k_proj_t_mfma(const bf16* __restrict__ AT,
        const bf16* __restrict__ Wb, const void* __restrict__ Bv,
        const bf16* __restrict__ x2, void* __restrict__ out,
        const int* __restrict__ flag, int m0){
  const bool f32in = flag[0] != 0;
  const int o0 = blockIdx.x * 128;
  const int tp = blockIdx.y;            // t-pair
  const int mg0 = blockIdx.z * 32;      // m base (32 | 576)
  const int tid = threadIdx.x, lane = tid & 63;
  const int wm = (tid >> 6) & 1, wn = tid >> 7;
  const int r15 = lane & 15, quad = lane >> 4;
  __shared__ bf16 As[128*72];
  __shared__ bf16 Bs[64*72];
  v4f acc[4][2];
  #pragma unroll
  for (int i = 0; i < 4; ++i)
    #pragma unroll
    for (int j = 0; j < 2; ++j) acc[i][j] = (v4f){0.f,0.f,0.f,0.f};
  for (int kc = 0; kc < 512; kc += 64){
    __syncthreads();
    #pragma unroll
    for (int r = 0; r < 8; ++r){
      int e4 = (tid + 256*r)*4;
      int row = e4 >> 6, k = e4 & 63;
      stage4b(&Wb[(size_t)(o0+row)*512 + kc + k], &As[row*72 + k]);
    }
    #pragma unroll
    for (int r = 0; r < 4; ++r){
      int e4 = (tid + 256*r)*4;
      int row = e4 >> 6, k = e4 & 63;
      stage4b(&AT[(size_t)(mg0 + (row & 31))*8192 + (tp*2 + (row >> 5))*512 + kc + k],
              &Bs[row*72 + k]);
    }
    __syncthreads();
    #pragma unroll
    for (int ks = 0; ks < 2; ++ks){
      v8s a[4], b[2];
      #pragma unroll
      for (int mi = 0; mi < 4; ++mi)
        a[mi] = *(const v8s*)&As[(wm*64 + mi*16 + r15)*72 + ks*32 + quad*8];
      #pragma unroll
      for (int ni = 0; ni < 2; ++ni)
        b[ni] = *(const v8s*)&Bs[(wn*32 + ni*16 + r15)*72 + ks*32 + quad*8];
      #pragma unroll
      for (int mi = 0; mi < 4; ++mi)
        #pragma unroll
        for (int ni = 0; ni < 2; ++ni)
          acc[mi][ni] = __builtin_amdgcn_mfma_f32_16x16x32_bf16(a[mi], b[ni], acc[mi][ni], 0, 0, 0);
    }
  }
  const int tt = tp*2 + wn;
  #pragma unroll
  for (int mi = 0; mi < 4; ++mi)
    #pragma unroll
    for (int rg = 0; rg < 4; ++rg){
      int o = o0 + wm*64 + mi*16 + quad*4 + rg;
      float bia = ldin(Bv, o, f32in);
      #pragma unroll
      for (int ni = 0; ni < 2; ++ni){
        int m = m0 + mg0 + ni*16 + r15;
        int b = m / 576, l = m - b*576;
        size_t addr = ((size_t)(b*512 + o)*16 + tt)*576 + l;
        float val = acc[mi][ni][rg] + bia + b2f(x2[addr]);
        if (f32in) ((float*)out)[addr] = val;
        else       ((bf16*)out)[addr] = f2b(val);
      }
    }
}

// ----------------------------------------------------------------
extern "C" void kernel_launch(void* const* d_in, const int* in_sizes, int n_in,
                              void* d_out, int out_size, void* d_ws, size_t ws_size,
                              hipStream_t stream){
  const void* x   = d_in[0];
  const void* nsw = d_in[1];
  const void* nsb = d_in[2];
  const void* qsw = d_in[3];
  const void* qsb = d_in[4];
  const void* psw = d_in[5];
  const void* psb = d_in[6];
  const void* ntw = d_in[7];
  const void* ntb = d_in[8];
  const void* qtw = d_in[9];
  const void* qtb = d_in[10];
  const void* ptw = d_in[11];
  const void* ptb = d_in[12];
  const void* rpk = d_in[13];
  const void* rpv = d_in[14];

  // Chunking and x2T gate from ws_size (constant across calls -> graph-safe).
  const size_t S_full = (size_t)32*294912;
  const size_t need_full = 256 + (S_full*5 + 9437184)*2;
  const size_t need_T    = 256 + (S_full*5 + (size_t)2*9437184)*2;  // +18.9 MB for x2T
  const int NCH = (ws_size >= need_full) ? 32 : 8;
  const int MCH = (NCH == 32) ? 1152 : 288;
  const size_t S = (size_t)NCH*294912;
  const int useT = (NCH == 32 && ws_size >= need_T) ? 1 : 0;

  int*  flag = (int*)d_ws;
  bf16* A  = (bf16*)((char*)d_ws + 256);   // S: xnT_s / xnT_t
  bf16* A2 = A  + S;                        // S: attT_s / attT_t (+ transient W copy)
  bf16* Bq = A2 + S;                        // 3S: qkv (+ transient W copies)
  bf16* Cx = Bq + 3*S;                      // 9,437,184: x2 residual
  bf16* Cx2 = Cx + 9437184;                 // 9,437,184: x2T [m][t][c] (if useT)
  const size_t kOff = S, vOff = 2*S;
  bf16* Wcv  = A2;
  bf16* Wcv2 = Bq;

  k_detect<<<1, 64, 0, stream>>>(x, flag);

  for (int n0 = 0; n0 < 32; n0 += NCH){
    k_gn_s       <<<dim3(32, NCH),   256, 0, stream>>>(x, nsw, nsb, A, flag, n0);
    k_cvtw       <<<dim3(768),       256, 0, stream>>>(qsw, Wcv, 196608, flag);
    k_gemm_qkv   <<<dim3(NCH*54),    256, 0, stream>>>(A, Wcv, qsb, Bq, flag, kOff, vOff, 0);
    k_attn_s_mfma<<<dim3(72*NCH),    256, 0, stream>>>(Bq, A2, kOff, vOff);
    // proj_s weight pre-convert into Bq (qkv dead after attn_s)
    k_cvtw       <<<dim3(256),       256, 0, stream>>>(psw, Bq, 65536, flag);
    k_proj_s_mfma<<<dim3(4, 9, NCH), 256, 0, stream>>>(A2, Bq, psb, x, Cx, Cx2, useT, flag, n0);
  }
  for (int m0 = 0; m0 < 1152; m0 += MCH){
    if (useT) k_gn_t2<<<dim3(MCH),   256, 0, stream>>>(Cx2, ntw, ntb, A, flag, m0);
    else      k_gn_t <<<dim3(MCH),   256, 0, stream>>>(Cx,  ntw, ntb, A, flag, m0);
    k_cvtw       <<<dim3(768),       256, 0, stream>>>(qtw, Wcv, 196608, flag);
    k_gemm_qkv   <<<dim3((MCH/2)*3), 256, 0, stream>>>(A, Wcv, qtb, Bq, flag, 0, 0, 1);
    k_attn_t     <<<dim3(8, MCH),    256, 0, stream>>>(Bq, rpk, rpv, A2, flag);
    k_cvtw       <<<dim3(256),       256, 0, stream>>>(ptw, Wcv2, 65536, flag);
    k_proj_t_mfma<<<dim3(4, 8, MCH/32), 256, 0, stream>>>(A2, Wcv2, ptb, Cx, d_out, flag, m0);
  }
}